// Round 6
// baseline (450.225 us; speedup 1.0000x reference)
//
#include <hip/hip_runtime.h>
#include <hip/hip_bf16.h>

#define H 128
#define BPAD 4608            // padded per-bucket capacity (mean 4096, ~8 sigma)
#define EPB 4096             // edges per scatter block
#define HP 136               // padded LDS row (shorts): 272B = 16B-aligned, banks spread

typedef __attribute__((ext_vector_type(8))) short bf16x8;
typedef __attribute__((ext_vector_type(4))) float f32x4;

static __device__ __forceinline__ unsigned short f2bf(float f) {
    unsigned u = __float_as_uint(f);
    u += 0x7FFFu + ((u >> 16) & 1u);          // round-to-nearest-even
    return (unsigned short)(u >> 16);
}
static __device__ __forceinline__ float bflo(unsigned u) {
    return __uint_as_float(u << 16);
}
static __device__ __forceinline__ float bfhi(unsigned u) {
    return __uint_as_float(u & 0xFFFF0000u);
}
static __device__ __forceinline__ unsigned packbf(float a, float b) {
    return (unsigned)f2bf(a) | ((unsigned)f2bf(b) << 16);
}

// ---------------------------------------------------------------------------
// prep: transposed bf16 weights  Wt[c][k] = bf16(W[k][c])  (+ combined wc, bc)
// ---------------------------------------------------------------------------
__global__ __launch_bounds__(256) void prep_weights_t(
        const float* __restrict__ wl1, const float* __restrict__ w01,
        const float* __restrict__ w11, const float* __restrict__ bl1,
        const float* __restrict__ b01, const float* __restrict__ b11,
        const float* __restrict__ wl0, const float* __restrict__ w00,
        const float* __restrict__ w10, const float* __restrict__ bl0,
        const float* __restrict__ b00, const float* __restrict__ b10,
        const float* __restrict__ w_out,
        unsigned short* __restrict__ Wt_l1, unsigned short* __restrict__ Wt_c1,
        unsigned short* __restrict__ Wt_l0, unsigned short* __restrict__ Wt_c0,
        unsigned short* __restrict__ Wt_o,
        float* __restrict__ bc1, float* __restrict__ bc0) {
    int i = blockIdx.x * 256 + threadIdx.x;     // i = k*H + c
    if (i < H * H) {
        int k = i >> 7, c = i & (H - 1);
        int t = c * H + k;
        Wt_l1[t] = f2bf(wl1[i]);
        Wt_c1[t] = f2bf(w01[i] + w11[i]);
        Wt_l0[t] = f2bf(wl0[i]);
        Wt_c0[t] = f2bf(w00[i] + w10[i]);
        Wt_o[t]  = f2bf(w_out[i]);
        if (i < H) {
            bc1[i] = bl1[i] + b01[i] + b11[i];
            bc0[i] = bl0[i] + b00[i] + b10[i];
        }
    }
}

// ---------------------------------------------------------------------------
// CSR phase 1: coarse-bucket scatter.  bucket = dst>>8 (256 nodes/bucket).
// ---------------------------------------------------------------------------
__global__ __launch_bounds__(256) void bucket_scatter(const int* __restrict__ edge, int E,
                                                      int* __restrict__ gcur,
                                                      int* __restrict__ packed) {
    __shared__ int lhist[512];
    __shared__ int lcur[512];
    int tid = threadIdx.x;
    lhist[tid] = 0;
    lhist[tid + 256] = 0;
    __syncthreads();

    int e0 = blockIdx.x * EPB;
    int d[16], s[16];
    #pragma unroll
    for (int j = 0; j < 16; ++j) {
        int e = e0 + j * 256 + tid;
        bool v = (e < E);
        d[j] = v ? edge[e] : -1;
        s[j] = v ? edge[E + e] : 0;
        if (v) atomicAdd(&lhist[d[j] >> 8], 1);
    }
    __syncthreads();

    for (int i = tid; i < 512; i += 256) {
        int c = lhist[i];
        lcur[i] = (c > 0) ? atomicAdd(&gcur[i], c) : 0;
    }
    __syncthreads();

    #pragma unroll
    for (int j = 0; j < 16; ++j) {
        if (d[j] >= 0) {
            int b = d[j] >> 8;
            int p = atomicAdd(&lcur[b], 1);
            if (p < BPAD)
                packed[(size_t)b * BPAD + p] = (s[j] << 8) | (d[j] & 255);
        }
    }
}

// ---------------------------------------------------------------------------
// CSR phase 2: per-bucket fine build -> nodeinfo + sorted col
// ---------------------------------------------------------------------------
__global__ __launch_bounds__(256) void bucket_build(const int* __restrict__ gcur,
                                                    const int* __restrict__ packed,
                                                    int* __restrict__ col,
                                                    int2* __restrict__ nodeinfo, int n) {
    __shared__ int hist[256];
    __shared__ int off[256];
    int b = blockIdx.x;
    int tid = threadIdx.x;
    int L = gcur[b];
    if (L > BPAD) L = BPAD;
    hist[tid] = 0;
    __syncthreads();

    const int* base = packed + (size_t)b * BPAD;
    for (int i = tid; i < L; i += 256)
        atomicAdd(&hist[base[i] & 255], 1);
    __syncthreads();

    int v = hist[tid];
    off[tid] = v;
    __syncthreads();
    for (int dd = 1; dd < 256; dd <<= 1) {
        int t = (tid >= dd) ? off[tid - dd] : 0;
        __syncthreads();
        off[tid] += t;
        __syncthreads();
    }
    int excl = off[tid] - v;

    int node = b * 256 + tid;
    if (node < n)
        nodeinfo[node] = make_int2(b * BPAD + excl, v);

    hist[tid] = excl;           // reuse as cursor
    __syncthreads();
    for (int i = tid; i < L; i += 256) {
        int pk = base[i];
        int p = atomicAdd(&hist[pk & 255], 1);
        col[(size_t)b * BPAD + p] = pk >> 8;
    }
}

// ---------------------------------------------------------------------------
// K1: dual MFMA GEMM from fp32 A:  T(bf16) = A@W1 ; U(bf16) = A@W2 + bias
// ---------------------------------------------------------------------------
__global__ __launch_bounds__(256) void gemm_dual_mfma_x(
        const float* __restrict__ A,
        const unsigned short* __restrict__ Wt1,
        const unsigned short* __restrict__ Wt2,
        const float* __restrict__ bias,
        unsigned short* __restrict__ T,
        unsigned short* __restrict__ U, int M) {
    int tid = threadIdx.x;
    int wave = tid >> 6;
    int lane = tid & 63;
    int r0 = blockIdx.x * 64 + wave * 16;
    int lrow = lane & 15;
    int koff = (lane >> 4) * 8;

    f32x4 accT[8] = {};
    f32x4 accU[8] = {};

    int arow = r0 + lrow;
    if (arow >= M) arow = M - 1;
    const float* Arow = A + (size_t)arow * H;

    for (int kt = 0; kt < 4; ++kt) {
        int k = kt * 32 + koff;
        float4 a0 = *(const float4*)(Arow + k);
        float4 a1 = *(const float4*)(Arow + k + 4);
        bf16x8 af;
        af[0] = (short)f2bf(a0.x); af[1] = (short)f2bf(a0.y);
        af[2] = (short)f2bf(a0.z); af[3] = (short)f2bf(a0.w);
        af[4] = (short)f2bf(a1.x); af[5] = (short)f2bf(a1.y);
        af[6] = (short)f2bf(a1.z); af[7] = (short)f2bf(a1.w);
        #pragma unroll
        for (int nt = 0; nt < 8; ++nt) {
            int c = nt * 16 + lrow;
            bf16x8 b1 = *(const bf16x8*)(Wt1 + (size_t)c * H + k);
            bf16x8 b2 = *(const bf16x8*)(Wt2 + (size_t)c * H + k);
            accT[nt] = __builtin_amdgcn_mfma_f32_16x16x32_bf16(af, b1, accT[nt], 0, 0, 0);
            accU[nt] = __builtin_amdgcn_mfma_f32_16x16x32_bf16(af, b2, accU[nt], 0, 0, 0);
        }
    }

    int orow = r0 + (lane >> 4) * 4;
    #pragma unroll
    for (int nt = 0; nt < 8; ++nt) {
        int c = nt * 16 + lrow;
        float bv = bias[c];
        #pragma unroll
        for (int i = 0; i < 4; ++i) {
            int r = orow + i;
            if (r < M) {
                T[(size_t)r * H + c] = f2bf(accT[nt][i]);
                U[(size_t)r * H + c] = f2bf(accU[nt][i] + bv);
            }
        }
    }
}

// ---------------------------------------------------------------------------
// Phase A helper: gather h rows into LDS (bf16, padded stride HP)
//   h[r] = relu( U[r] + sum_{src in adj(r)} T[src] )
// ---------------------------------------------------------------------------
static __device__ __forceinline__ void gather_rows_to_lds(
        const unsigned short* __restrict__ T,
        const unsigned short* __restrict__ U,
        const int2* __restrict__ nodeinfo,
        const int* __restrict__ col,
        unsigned short* __restrict__ hs,      // [64][HP]
        int row0, int M) {
    int tid = threadIdx.x;
    int gid = tid >> 4;
    int l16 = tid & 15;
    for (int sub = 0; sub < 4; ++sub) {
        int lr = sub * 16 + gid;              // 0..63
        int r = row0 + lr;
        float a[8] = {0, 0, 0, 0, 0, 0, 0, 0};
        if (r < M) {
            uint4 uv = *(const uint4*)(U + (size_t)r * H + l16 * 8);
            a[0] = bflo(uv.x); a[1] = bfhi(uv.x);
            a[2] = bflo(uv.y); a[3] = bfhi(uv.y);
            a[4] = bflo(uv.z); a[5] = bfhi(uv.z);
            a[6] = bflo(uv.w); a[7] = bfhi(uv.w);
            int2 info = nodeinfo[r];
            for (int e0 = 0; e0 < info.y; e0 += 16) {
                int myc = (e0 + l16 < info.y) ? col[info.x + e0 + l16] : 0;
                int cnt = min(16, info.y - e0);
                for (int j = 0; j < cnt; ++j) {
                    int src = __shfl(myc, j, 16);
                    uint4 v = *(const uint4*)(T + (size_t)src * H + l16 * 8);
                    a[0] += bflo(v.x); a[1] += bfhi(v.x);
                    a[2] += bflo(v.y); a[3] += bfhi(v.y);
                    a[4] += bflo(v.z); a[5] += bfhi(v.z);
                    a[6] += bflo(v.w); a[7] += bfhi(v.w);
                }
            }
            #pragma unroll
            for (int j = 0; j < 8; ++j) a[j] = fmaxf(a[j], 0.f);
        }
        uint4 pk;
        pk.x = packbf(a[0], a[1]);
        pk.y = packbf(a[2], a[3]);
        pk.z = packbf(a[4], a[5]);
        pk.w = packbf(a[6], a[7]);
        *(uint4*)(hs + (size_t)lr * HP + l16 * 8) = pk;
    }
}

// ---------------------------------------------------------------------------
// K2: fused gather + dual MFMA:  h = gather(T,U) ; T2 = h@W1 ; U = h@W2 + bias
// U updated in place (rows are block-private).
// ---------------------------------------------------------------------------
__global__ __launch_bounds__(256) void fused_gather_dual(
        const unsigned short* __restrict__ T,
        unsigned short* __restrict__ U,
        const int2* __restrict__ nodeinfo,
        const int* __restrict__ col,
        const unsigned short* __restrict__ Wt1,
        const unsigned short* __restrict__ Wt2,
        const float* __restrict__ bias,
        unsigned short* __restrict__ T2, int M) {
    __shared__ unsigned short hs[64 * HP];
    int row0 = blockIdx.x * 64;
    gather_rows_to_lds(T, U, nodeinfo, col, hs, row0, M);
    __syncthreads();

    int tid = threadIdx.x;
    int wave = tid >> 6;
    int lane = tid & 63;
    int lrow = lane & 15;
    int koff = (lane >> 4) * 8;

    f32x4 accT[8] = {};
    f32x4 accU[8] = {};
    const unsigned short* hrow = hs + (size_t)(wave * 16 + lrow) * HP;

    for (int kt = 0; kt < 4; ++kt) {
        int k = kt * 32 + koff;
        bf16x8 af = *(const bf16x8*)(hrow + k);
        #pragma unroll
        for (int nt = 0; nt < 8; ++nt) {
            int c = nt * 16 + lrow;
            bf16x8 b1 = *(const bf16x8*)(Wt1 + (size_t)c * H + k);
            bf16x8 b2 = *(const bf16x8*)(Wt2 + (size_t)c * H + k);
            accT[nt] = __builtin_amdgcn_mfma_f32_16x16x32_bf16(af, b1, accT[nt], 0, 0, 0);
            accU[nt] = __builtin_amdgcn_mfma_f32_16x16x32_bf16(af, b2, accU[nt], 0, 0, 0);
        }
    }

    int orow = row0 + wave * 16 + (lane >> 4) * 4;
    #pragma unroll
    for (int nt = 0; nt < 8; ++nt) {
        int c = nt * 16 + lrow;
        float bv = bias[c];
        #pragma unroll
        for (int i = 0; i < 4; ++i) {
            int r = orow + i;
            if (r < M) {
                T2[(size_t)r * H + c] = f2bf(accT[nt][i]);
                U[(size_t)r * H + c] = f2bf(accU[nt][i] + bv);
            }
        }
    }
}

// ---------------------------------------------------------------------------
// K3: fused gather + output GEMM:  h = gather(T,U) ; out = h@W + bias (f32)
// ---------------------------------------------------------------------------
__global__ __launch_bounds__(256) void fused_gather_out(
        const unsigned short* __restrict__ T,
        const unsigned short* __restrict__ U,
        const int2* __restrict__ nodeinfo,
        const int* __restrict__ col,
        const unsigned short* __restrict__ Wt,
        const float* __restrict__ bias,
        float* __restrict__ out, int M) {
    __shared__ unsigned short hs[64 * HP];
    int row0 = blockIdx.x * 64;
    gather_rows_to_lds(T, U, nodeinfo, col, hs, row0, M);
    __syncthreads();

    int tid = threadIdx.x;
    int wave = tid >> 6;
    int lane = tid & 63;
    int lrow = lane & 15;
    int koff = (lane >> 4) * 8;

    f32x4 acc[8] = {};
    const unsigned short* hrow = hs + (size_t)(wave * 16 + lrow) * HP;

    for (int kt = 0; kt < 4; ++kt) {
        int k = kt * 32 + koff;
        bf16x8 af = *(const bf16x8*)(hrow + k);
        #pragma unroll
        for (int nt = 0; nt < 8; ++nt) {
            int c = nt * 16 + lrow;
            bf16x8 b = *(const bf16x8*)(Wt + (size_t)c * H + k);
            acc[nt] = __builtin_amdgcn_mfma_f32_16x16x32_bf16(af, b, acc[nt], 0, 0, 0);
        }
    }

    int orow = row0 + wave * 16 + (lane >> 4) * 4;
    #pragma unroll
    for (int nt = 0; nt < 8; ++nt) {
        int c = nt * 16 + lrow;
        float bv = bias[c];
        #pragma unroll
        for (int i = 0; i < 4; ++i) {
            int r = orow + i;
            if (r < M)
                out[(size_t)r * H + c] = acc[nt][i] + bv;
        }
    }
}

extern "C" void kernel_launch(void* const* d_in, const int* in_sizes, int n_in,
                              void* d_out, int out_size, void* d_ws, size_t ws_size,
                              hipStream_t stream) {
    const float* x_A  = (const float*)d_in[0];
    const int* edge_r0 = (const int*)d_in[2];
    const int* edge_r1 = (const int*)d_in[3];
    const float* wl0 = (const float*)d_in[4];
    const float* bl0 = (const float*)d_in[5];
    const float* w00 = (const float*)d_in[6];
    const float* b00 = (const float*)d_in[7];
    const float* w10 = (const float*)d_in[8];
    const float* b10 = (const float*)d_in[9];
    const float* wl1 = (const float*)d_in[10];
    const float* bl1 = (const float*)d_in[11];
    const float* w01 = (const float*)d_in[12];
    const float* b01 = (const float*)d_in[13];
    const float* w11 = (const float*)d_in[14];
    const float* b11 = (const float*)d_in[15];
    const float* w_out = (const float*)d_in[16];
    const float* b_out = (const float*)d_in[17];

    const int N  = in_sizes[0] / H;       // 100000
    const int E0 = in_sizes[2] / 2;
    const int E1 = in_sizes[3] / 2;
    const int NB = (N + 255) / 256;       // 391 coarse buckets

    char* ws = (char*)d_ws;
    unsigned short* U  = (unsigned short*)ws;            ws += (size_t)N * H * sizeof(short);
    unsigned short* T2 = (unsigned short*)ws;            ws += (size_t)N * H * sizeof(short);
    int*   col        = (int*)ws;                        ws += (size_t)NB * BPAD * sizeof(int);
    int2*  nodeinfo   = (int2*)ws;                       ws += (size_t)N * sizeof(int2);
    int*   gcur       = (int*)ws;                        ws += 512 * sizeof(int);
    unsigned short* Wt_l1 = (unsigned short*)ws;         ws += H * H * sizeof(short);
    unsigned short* Wt_c1 = (unsigned short*)ws;         ws += H * H * sizeof(short);
    unsigned short* Wt_l0 = (unsigned short*)ws;         ws += H * H * sizeof(short);
    unsigned short* Wt_c0 = (unsigned short*)ws;         ws += H * H * sizeof(short);
    unsigned short* Wt_o  = (unsigned short*)ws;         ws += H * H * sizeof(short);
    float* bc1        = (float*)ws;                      ws += H * sizeof(float);
    float* bc0        = (float*)ws;                      ws += H * sizeof(float);

    // d_out overlays: T1 (bf16, 25.6 MB) at offset 0; packed (7.2 MB) above it.
    // Both are dead before fused_gather_out writes all of d_out as f32.
    unsigned short* T1 = (unsigned short*)d_out;
    int* packed = (int*)((char*)d_out + (size_t)N * H * sizeof(unsigned short));

    prep_weights_t<<<(H * H + 255) / 256, 256, 0, stream>>>(
        wl1, w01, w11, bl1, b01, b11, wl0, w00, w10, bl0, b00, b10, w_out,
        Wt_l1, Wt_c1, Wt_l0, Wt_c0, Wt_o, bc1, bc0);

    const int gemmBlocks = (N + 63) / 64;

    // ---- CSR for relation r1 ----
    hipMemsetAsync(gcur, 0, 512 * sizeof(int), stream);
    bucket_scatter<<<(E1 + EPB - 1) / EPB, 256, 0, stream>>>(edge_r1, E1, gcur, packed);
    bucket_build<<<NB, 256, 0, stream>>>(gcur, packed, col, nodeinfo, N);

    // ---- K1: T1 = bf16(x_A@wl1) ; U = bf16(x_A@wc1 + bc1) ----
    gemm_dual_mfma_x<<<gemmBlocks, 256, 0, stream>>>(x_A, Wt_l1, Wt_c1, bc1, T1, U, N);

    // ---- K2: h1 = relu(U + gather_r1(T1)); T2 = bf16(h1@wl0); U = bf16(h1@wc0+bc0) ----
    fused_gather_dual<<<gemmBlocks, 256, 0, stream>>>(T1, U, nodeinfo, col,
                                                      Wt_l0, Wt_c0, bc0, T2, N);

    // ---- CSR for relation r0 (T1/packed in d_out are now dead) ----
    hipMemsetAsync(gcur, 0, 512 * sizeof(int), stream);
    bucket_scatter<<<(E0 + EPB - 1) / EPB, 256, 0, stream>>>(edge_r0, E0, gcur, packed);
    bucket_build<<<NB, 256, 0, stream>>>(gcur, packed, col, nodeinfo, N);

    // ---- K3: h2 = relu(U + gather_r0(T2)); out = h2@w_out + b_out (f32) ----
    fused_gather_out<<<gemmBlocks, 256, 0, stream>>>(T2, U, nodeinfo, col,
                                                     Wt_o, b_out, (float*)d_out, N);
}

// Round 9
// 380.207 us; speedup vs baseline: 1.1842x; 1.1842x over previous
//
#include <hip/hip_runtime.h>
#include <hip/hip_bf16.h>

#define H 128
#define BPAD 4608            // padded per-bucket capacity (mean 4096, ~8 sigma)
#define EPB 4096             // edges per scatter block
#define HP 136               // padded LDS row stride (shorts)

typedef __attribute__((ext_vector_type(8))) short bf16x8;
typedef __attribute__((ext_vector_type(4))) float f32x4;

static __device__ __forceinline__ unsigned short f2bf(float f) {
    unsigned u = __float_as_uint(f);
    u += 0x7FFFu + ((u >> 16) & 1u);          // round-to-nearest-even
    return (unsigned short)(u >> 16);
}
static __device__ __forceinline__ float bflo(unsigned u) {
    return __uint_as_float(u << 16);
}
static __device__ __forceinline__ float bfhi(unsigned u) {
    return __uint_as_float(u & 0xFFFF0000u);
}
static __device__ __forceinline__ unsigned packbf(float a, float b) {
    return (unsigned)f2bf(a) | ((unsigned)f2bf(b) << 16);
}

// ---------------------------------------------------------------------------
// prep: transposed bf16 weights  Wt[c][k] = bf16(W[k][c])  (+ combined wc, bc)
// ---------------------------------------------------------------------------
__global__ __launch_bounds__(256) void prep_weights_t(
        const float* __restrict__ wl1, const float* __restrict__ w01,
        const float* __restrict__ w11, const float* __restrict__ bl1,
        const float* __restrict__ b01, const float* __restrict__ b11,
        const float* __restrict__ wl0, const float* __restrict__ w00,
        const float* __restrict__ w10, const float* __restrict__ bl0,
        const float* __restrict__ b00, const float* __restrict__ b10,
        const float* __restrict__ w_out,
        unsigned short* __restrict__ Wt_l1, unsigned short* __restrict__ Wt_c1,
        unsigned short* __restrict__ Wt_l0, unsigned short* __restrict__ Wt_c0,
        unsigned short* __restrict__ Wt_o,
        float* __restrict__ bc1, float* __restrict__ bc0) {
    int i = blockIdx.x * 256 + threadIdx.x;     // i = k*H + c
    if (i < H * H) {
        int k = i >> 7, c = i & (H - 1);
        int t = c * H + k;
        Wt_l1[t] = f2bf(wl1[i]);
        Wt_c1[t] = f2bf(w01[i] + w11[i]);
        Wt_l0[t] = f2bf(wl0[i]);
        Wt_c0[t] = f2bf(w00[i] + w10[i]);
        Wt_o[t]  = f2bf(w_out[i]);
        if (i < H) {
            bc1[i] = bl1[i] + b01[i] + b11[i];
            bc0[i] = bl0[i] + b00[i] + b10[i];
        }
    }
}

// ---------------------------------------------------------------------------
// CSR phase 1: coarse-bucket scatter.  bucket = dst>>8 (256 nodes/bucket).
// ---------------------------------------------------------------------------
__global__ __launch_bounds__(256) void bucket_scatter(const int* __restrict__ edge, int E,
                                                      int* __restrict__ gcur,
                                                      int* __restrict__ packed) {
    __shared__ int lhist[512];
    __shared__ int lcur[512];
    int tid = threadIdx.x;
    lhist[tid] = 0;
    lhist[tid + 256] = 0;
    __syncthreads();

    int e0 = blockIdx.x * EPB;
    int d[16], s[16];
    #pragma unroll
    for (int j = 0; j < 16; ++j) {
        int e = e0 + j * 256 + tid;
        bool v = (e < E);
        d[j] = v ? edge[e] : -1;
        s[j] = v ? edge[E + e] : 0;
        if (v) atomicAdd(&lhist[d[j] >> 8], 1);
    }
    __syncthreads();

    for (int i = tid; i < 512; i += 256) {
        int c = lhist[i];
        lcur[i] = (c > 0) ? atomicAdd(&gcur[i], c) : 0;
    }
    __syncthreads();

    #pragma unroll
    for (int j = 0; j < 16; ++j) {
        if (d[j] >= 0) {
            int b = d[j] >> 8;
            int p = atomicAdd(&lcur[b], 1);
            if (p < BPAD)
                packed[(size_t)b * BPAD + p] = (s[j] << 8) | (d[j] & 255);
        }
    }
}

// ---------------------------------------------------------------------------
// CSR phase 2: per-bucket fine build -> nodeinfo + col
// ---------------------------------------------------------------------------
__global__ __launch_bounds__(256) void bucket_build(const int* __restrict__ gcur,
                                                    const int* __restrict__ packed,
                                                    int* __restrict__ col,
                                                    int2* __restrict__ nodeinfo, int n) {
    __shared__ int hist[256];
    __shared__ int off[256];
    int b = blockIdx.x;
    int tid = threadIdx.x;
    int L = gcur[b];
    if (L > BPAD) L = BPAD;
    hist[tid] = 0;
    __syncthreads();

    const int* base = packed + (size_t)b * BPAD;
    for (int i = tid; i < L; i += 256)
        atomicAdd(&hist[base[i] & 255], 1);
    __syncthreads();

    int v = hist[tid];
    off[tid] = v;
    __syncthreads();
    for (int dd = 1; dd < 256; dd <<= 1) {
        int t = (tid >= dd) ? off[tid - dd] : 0;
        __syncthreads();
        off[tid] += t;
        __syncthreads();
    }
    int excl = off[tid] - v;

    int node = b * 256 + tid;
    if (node < n)
        nodeinfo[node] = make_int2(b * BPAD + excl, v);

    hist[tid] = excl;           // reuse as cursor
    __syncthreads();
    for (int i = tid; i < L; i += 256) {
        int pk = base[i];
        int p = atomicAdd(&hist[pk & 255], 1);
        col[(size_t)b * BPAD + p] = pk >> 8;
    }
}

// ---------------------------------------------------------------------------
// dual MFMA GEMM, 512 threads: wave = (row-tile rg 0..3) x (col-half ch 0..1)
// acc = 32 regs/wave -> ~90 total regs -> 4 waves/SIMD.
// T(bf16) = A@W1 ; U(bf16) = A@W2 + bias.  Safe for U == A (all reads of A
// complete before the first __syncthreads; stores follow it).
// Epilogue staged through LDS -> coalesced uint4 stores.
// 64x128 shorts = 64 rows x 16 uint4-chunks -> idx>>4 / idx&15.
// ---------------------------------------------------------------------------
template <int AF32>
__global__ __launch_bounds__(512) void gemm_dual_v2(
        const void* __restrict__ Ain,
        const unsigned short* __restrict__ Wt1,
        const unsigned short* __restrict__ Wt2,
        const float* __restrict__ bias,
        unsigned short* __restrict__ T,
        unsigned short* __restrict__ U, int M) {
    __shared__ unsigned short hs[64 * HP];
    int tid = threadIdx.x;
    int wave = tid >> 6;
    int lane = tid & 63;
    int rg = wave >> 1;          // row tile 0..3 (16 rows each)
    int ch = wave & 1;           // col half 0..1 (64 cols each)
    int lrow = lane & 15;
    int koff = (lane >> 4) * 8;
    int row0 = blockIdx.x * 64;

    int arow = row0 + rg * 16 + lrow;
    if (arow >= M) arow = M - 1;          // clamp reads; stores guarded

    f32x4 accT[4] = {};
    f32x4 accU[4] = {};

    #pragma unroll
    for (int kt = 0; kt < 4; ++kt) {
        int k = kt * 32 + koff;
        bf16x8 af;
        if (AF32) {
            const float* Arow = (const float*)Ain + (size_t)arow * H;
            float4 a0 = *(const float4*)(Arow + k);
            float4 a1 = *(const float4*)(Arow + k + 4);
            af[0] = (short)f2bf(a0.x); af[1] = (short)f2bf(a0.y);
            af[2] = (short)f2bf(a0.z); af[3] = (short)f2bf(a0.w);
            af[4] = (short)f2bf(a1.x); af[5] = (short)f2bf(a1.y);
            af[6] = (short)f2bf(a1.z); af[7] = (short)f2bf(a1.w);
        } else {
            af = *(const bf16x8*)((const unsigned short*)Ain + (size_t)arow * H + k);
        }
        #pragma unroll
        for (int nt = 0; nt < 4; ++nt) {
            int c = ch * 64 + nt * 16 + lrow;
            bf16x8 b1 = *(const bf16x8*)(Wt1 + (size_t)c * H + k);
            bf16x8 b2 = *(const bf16x8*)(Wt2 + (size_t)c * H + k);
            accT[nt] = __builtin_amdgcn_mfma_f32_16x16x32_bf16(af, b1, accT[nt], 0, 0, 0);
            accU[nt] = __builtin_amdgcn_mfma_f32_16x16x32_bf16(af, b2, accU[nt], 0, 0, 0);
        }
    }

    int erow = rg * 16 + (lane >> 4) * 4;    // C/D: col=lane&15, row=(lane>>4)*4+i
    // ---- T epilogue ----
    #pragma unroll
    for (int nt = 0; nt < 4; ++nt) {
        int c = ch * 64 + nt * 16 + lrow;
        #pragma unroll
        for (int i = 0; i < 4; ++i)
            hs[(erow + i) * HP + c] = f2bf(accT[nt][i]);
    }
    __syncthreads();
    #pragma unroll
    for (int q = 0; q < 2; ++q) {
        int idx = q * 512 + tid;             // 1024 chunks of 16B: 64 rows x 16 chunks
        int row = idx >> 4, c16 = idx & 15;
        int r = row0 + row;
        if (r < M)
            *(uint4*)(T + (size_t)r * H + c16 * 8) = *(const uint4*)(hs + row * HP + c16 * 8);
    }
    __syncthreads();
    // ---- U epilogue (bias added here) ----
    #pragma unroll
    for (int nt = 0; nt < 4; ++nt) {
        int c = ch * 64 + nt * 16 + lrow;
        float bv = bias[c];
        #pragma unroll
        for (int i = 0; i < 4; ++i)
            hs[(erow + i) * HP + c] = f2bf(accU[nt][i] + bv);
    }
    __syncthreads();
    #pragma unroll
    for (int q = 0; q < 2; ++q) {
        int idx = q * 512 + tid;
        int row = idx >> 4, c16 = idx & 15;
        int r = row0 + row;
        if (r < M)
            *(uint4*)(U + (size_t)r * H + c16 * 8) = *(const uint4*)(hs + row * HP + c16 * 8);
    }
}

// ---------------------------------------------------------------------------
// single MFMA GEMM, 512 threads:  out(f32) = A(bf16)@W + bias
// ---------------------------------------------------------------------------
__global__ __launch_bounds__(512) void gemm_single_v2(
        const unsigned short* __restrict__ A,
        const unsigned short* __restrict__ Wt,
        const float* __restrict__ bias,
        float* __restrict__ out, int M) {
    int tid = threadIdx.x;
    int wave = tid >> 6;
    int lane = tid & 63;
    int rg = wave >> 1;
    int ch = wave & 1;
    int lrow = lane & 15;
    int koff = (lane >> 4) * 8;
    int row0 = blockIdx.x * 64;

    int arow = row0 + rg * 16 + lrow;
    if (arow >= M) arow = M - 1;

    f32x4 acc[4] = {};

    #pragma unroll
    for (int kt = 0; kt < 4; ++kt) {
        int k = kt * 32 + koff;
        bf16x8 af = *(const bf16x8*)(A + (size_t)arow * H + k);
        #pragma unroll
        for (int nt = 0; nt < 4; ++nt) {
            int c = ch * 64 + nt * 16 + lrow;
            bf16x8 b = *(const bf16x8*)(Wt + (size_t)c * H + k);
            acc[nt] = __builtin_amdgcn_mfma_f32_16x16x32_bf16(af, b, acc[nt], 0, 0, 0);
        }
    }

    int orow = row0 + rg * 16 + (lane >> 4) * 4;
    #pragma unroll
    for (int nt = 0; nt < 4; ++nt) {
        int c = ch * 64 + nt * 16 + lrow;
        float bv = bias[c];
        #pragma unroll
        for (int i = 0; i < 4; ++i) {
            int r = orow + i;
            if (r < M)
                out[(size_t)r * H + c] = acc[nt][i] + bv;
        }
    }
}

// ---------------------------------------------------------------------------
// gather: U[g] = relu( U[g] + sum_{src in adj(g)} T[src] )  (all bf16, in place)
// ---------------------------------------------------------------------------
__global__ __launch_bounds__(256) void gather_relu_b(
        const unsigned short* __restrict__ T,
        const int2* __restrict__ nodeinfo,
        const int* __restrict__ col,
        unsigned short* __restrict__ U, int n) {
    int g = (int)((blockIdx.x * 256u + threadIdx.x) >> 4);
    int lane = threadIdx.x & 15;
    if (g >= n) return;
    int2 info = nodeinfo[g];
    unsigned short* Urow = U + (size_t)g * H + lane * 8;
    uint4 uv = *(const uint4*)Urow;
    float a[8];
    a[0] = bflo(uv.x); a[1] = bfhi(uv.x);
    a[2] = bflo(uv.y); a[3] = bfhi(uv.y);
    a[4] = bflo(uv.z); a[5] = bfhi(uv.z);
    a[6] = bflo(uv.w); a[7] = bfhi(uv.w);
    for (int e0 = 0; e0 < info.y; e0 += 16) {
        int myc = (e0 + lane < info.y) ? col[info.x + e0 + lane] : 0;
        int cnt = min(16, info.y - e0);
        for (int j = 0; j < cnt; ++j) {
            int src = __shfl(myc, j, 16);
            uint4 v = *(const uint4*)(T + (size_t)src * H + lane * 8);
            a[0] += bflo(v.x); a[1] += bfhi(v.x);
            a[2] += bflo(v.y); a[3] += bfhi(v.y);
            a[4] += bflo(v.z); a[5] += bfhi(v.z);
            a[6] += bflo(v.w); a[7] += bfhi(v.w);
        }
    }
    #pragma unroll
    for (int j = 0; j < 8; ++j) a[j] = fmaxf(a[j], 0.f);
    uint4 pk;
    pk.x = packbf(a[0], a[1]);
    pk.y = packbf(a[2], a[3]);
    pk.z = packbf(a[4], a[5]);
    pk.w = packbf(a[6], a[7]);
    *(uint4*)Urow = pk;
}

extern "C" void kernel_launch(void* const* d_in, const int* in_sizes, int n_in,
                              void* d_out, int out_size, void* d_ws, size_t ws_size,
                              hipStream_t stream) {
    const float* x_A  = (const float*)d_in[0];
    const int* edge_r0 = (const int*)d_in[2];
    const int* edge_r1 = (const int*)d_in[3];
    const float* wl0 = (const float*)d_in[4];
    const float* bl0 = (const float*)d_in[5];
    const float* w00 = (const float*)d_in[6];
    const float* b00 = (const float*)d_in[7];
    const float* w10 = (const float*)d_in[8];
    const float* b10 = (const float*)d_in[9];
    const float* wl1 = (const float*)d_in[10];
    const float* bl1 = (const float*)d_in[11];
    const float* w01 = (const float*)d_in[12];
    const float* b01 = (const float*)d_in[13];
    const float* w11 = (const float*)d_in[14];
    const float* b11 = (const float*)d_in[15];
    const float* w_out = (const float*)d_in[16];
    const float* b_out = (const float*)d_in[17];

    const int N  = in_sizes[0] / H;       // 100000
    const int E0 = in_sizes[2] / 2;
    const int E1 = in_sizes[3] / 2;
    const int NB = (N + 255) / 256;       // 391 coarse buckets

    char* ws = (char*)d_ws;
    unsigned short* U  = (unsigned short*)ws;            ws += (size_t)N * H * sizeof(short);
    unsigned short* T2 = (unsigned short*)ws;            ws += (size_t)N * H * sizeof(short);
    int*   col        = (int*)ws;                        ws += (size_t)NB * BPAD * sizeof(int);
    int2*  nodeinfo   = (int2*)ws;                       ws += (size_t)N * sizeof(int2);
    int*   gcur       = (int*)ws;                        ws += 512 * sizeof(int);
    unsigned short* Wt_l1 = (unsigned short*)ws;         ws += H * H * sizeof(short);
    unsigned short* Wt_c1 = (unsigned short*)ws;         ws += H * H * sizeof(short);
    unsigned short* Wt_l0 = (unsigned short*)ws;         ws += H * H * sizeof(short);
    unsigned short* Wt_c0 = (unsigned short*)ws;         ws += H * H * sizeof(short);
    unsigned short* Wt_o  = (unsigned short*)ws;         ws += H * H * sizeof(short);
    float* bc1        = (float*)ws;                      ws += H * sizeof(float);
    float* bc0        = (float*)ws;                      ws += H * sizeof(float);

    // d_out overlays: T1 (bf16, 25.6 MB) at offset 0; packed (7.2 MB) above it.
    // Both dead before gemm_single_v2 writes all of d_out as f32.
    unsigned short* T1 = (unsigned short*)d_out;
    int* packed = (int*)((char*)d_out + (size_t)N * H * sizeof(unsigned short));

    prep_weights_t<<<(H * H + 255) / 256, 256, 0, stream>>>(
        wl1, w01, w11, bl1, b01, b11, wl0, w00, w10, bl0, b00, b10, w_out,
        Wt_l1, Wt_c1, Wt_l0, Wt_c0, Wt_o, bc1, bc0);

    const int gemmBlocks = (N + 63) / 64;
    const int gatherBlocks = (N * 16 + 255) / 256;

    // ---- CSR r1 ----
    hipMemsetAsync(gcur, 0, 512 * sizeof(int), stream);
    bucket_scatter<<<(E1 + EPB - 1) / EPB, 256, 0, stream>>>(edge_r1, E1, gcur, packed);
    bucket_build<<<NB, 256, 0, stream>>>(gcur, packed, col, nodeinfo, N);

    // ---- K1: T1 = bf16(x_A@wl1) ; U = bf16(x_A@wc1 + bc1) ----
    gemm_dual_v2<1><<<gemmBlocks, 512, 0, stream>>>(x_A, Wt_l1, Wt_c1, bc1, T1, U, N);

    // ---- G1: h1 = relu(U + gather_r1(T1)) -> U ----
    gather_relu_b<<<gatherBlocks, 256, 0, stream>>>(T1, nodeinfo, col, U, N);

    // ---- CSR r0 ----
    hipMemsetAsync(gcur, 0, 512 * sizeof(int), stream);
    bucket_scatter<<<(E0 + EPB - 1) / EPB, 256, 0, stream>>>(edge_r0, E0, gcur, packed);
    bucket_build<<<NB, 256, 0, stream>>>(gcur, packed, col, nodeinfo, N);

    // ---- K2: T2 = bf16(h1@wl0) ; U = bf16(h1@wc0 + bc0) (in place) ----
    gemm_dual_v2<0><<<gemmBlocks, 512, 0, stream>>>(U, Wt_l0, Wt_c0, bc0, T2, U, N);

    // ---- G2: h2 = relu(U + gather_r0(T2)) -> U ----
    gather_relu_b<<<gatherBlocks, 256, 0, stream>>>(T2, nodeinfo, col, U, N);

    // ---- K3: out = h2 @ w_out + b_out (f32, overwrites all of d_out) ----
    gemm_single_v2<<<gemmBlocks, 512, 0, stream>>>(U, Wt_o, b_out, (float*)d_out, N);
}

// Round 11
// 281.628 us; speedup vs baseline: 1.5986x; 1.3500x over previous
//
#include <hip/hip_runtime.h>
#include <hip/hip_bf16.h>

#define H 128
#define BPAD 4608            // padded per-bucket capacity (mean 4096, ~8 sigma)
#define EPB 4096             // edges per scatter block
#define HP 136               // padded LDS row stride (shorts): 2-way banks on b128 reads
#define WROWS (2 * H)        // 256 weight rows staged (two matrices)

typedef __attribute__((ext_vector_type(8))) short bf16x8;
typedef __attribute__((ext_vector_type(4))) float f32x4;

static __device__ __forceinline__ unsigned short f2bf(float f) {
    unsigned u = __float_as_uint(f);
    u += 0x7FFFu + ((u >> 16) & 1u);          // round-to-nearest-even
    return (unsigned short)(u >> 16);
}
static __device__ __forceinline__ float bflo(unsigned u) {
    return __uint_as_float(u << 16);
}
static __device__ __forceinline__ float bfhi(unsigned u) {
    return __uint_as_float(u & 0xFFFF0000u);
}
static __device__ __forceinline__ unsigned packbf(float a, float b) {
    return (unsigned)f2bf(a) | ((unsigned)f2bf(b) << 16);
}

// ---------------------------------------------------------------------------
// prep: transposed bf16 weights  Wt[c][k] = bf16(W[k][c])  (+ combined wc, bc)
// ---------------------------------------------------------------------------
__global__ __launch_bounds__(256) void prep_weights_t(
        const float* __restrict__ wl1, const float* __restrict__ w01,
        const float* __restrict__ w11, const float* __restrict__ bl1,
        const float* __restrict__ b01, const float* __restrict__ b11,
        const float* __restrict__ wl0, const float* __restrict__ w00,
        const float* __restrict__ w10, const float* __restrict__ bl0,
        const float* __restrict__ b00, const float* __restrict__ b10,
        const float* __restrict__ w_out,
        unsigned short* __restrict__ Wt_l1, unsigned short* __restrict__ Wt_c1,
        unsigned short* __restrict__ Wt_l0, unsigned short* __restrict__ Wt_c0,
        unsigned short* __restrict__ Wt_o,
        float* __restrict__ bc1, float* __restrict__ bc0) {
    int i = blockIdx.x * 256 + threadIdx.x;     // i = k*H + c
    if (i < H * H) {
        int k = i >> 7, c = i & (H - 1);
        int t = c * H + k;
        Wt_l1[t] = f2bf(wl1[i]);
        Wt_c1[t] = f2bf(w01[i] + w11[i]);
        Wt_l0[t] = f2bf(wl0[i]);
        Wt_c0[t] = f2bf(w00[i] + w10[i]);
        Wt_o[t]  = f2bf(w_out[i]);
        if (i < H) {
            bc1[i] = bl1[i] + b01[i] + b11[i];
            bc0[i] = bl0[i] + b00[i] + b10[i];
        }
    }
}

// ---------------------------------------------------------------------------
// CSR phase 1: coarse-bucket scatter.  bucket = dst>>8 (256 nodes/bucket).
// ---------------------------------------------------------------------------
__global__ __launch_bounds__(256) void bucket_scatter(const int* __restrict__ edge, int E,
                                                      int* __restrict__ gcur,
                                                      int* __restrict__ packed) {
    __shared__ int lhist[512];
    __shared__ int lcur[512];
    int tid = threadIdx.x;
    lhist[tid] = 0;
    lhist[tid + 256] = 0;
    __syncthreads();

    int e0 = blockIdx.x * EPB;
    int d[16], s[16];
    #pragma unroll
    for (int j = 0; j < 16; ++j) {
        int e = e0 + j * 256 + tid;
        bool v = (e < E);
        d[j] = v ? edge[e] : -1;
        s[j] = v ? edge[E + e] : 0;
        if (v) atomicAdd(&lhist[d[j] >> 8], 1);
    }
    __syncthreads();

    for (int i = tid; i < 512; i += 256) {
        int c = lhist[i];
        lcur[i] = (c > 0) ? atomicAdd(&gcur[i], c) : 0;
    }
    __syncthreads();

    #pragma unroll
    for (int j = 0; j < 16; ++j) {
        if (d[j] >= 0) {
            int b = d[j] >> 8;
            int p = atomicAdd(&lcur[b], 1);
            if (p < BPAD)
                packed[(size_t)b * BPAD + p] = (s[j] << 8) | (d[j] & 255);
        }
    }
}

// ---------------------------------------------------------------------------
// CSR phase 2: per-bucket fine build -> nodeinfo + col
// ---------------------------------------------------------------------------
__global__ __launch_bounds__(256) void bucket_build(const int* __restrict__ gcur,
                                                    const int* __restrict__ packed,
                                                    int* __restrict__ col,
                                                    int2* __restrict__ nodeinfo, int n) {
    __shared__ int hist[256];
    __shared__ int off[256];
    int b = blockIdx.x;
    int tid = threadIdx.x;
    int L = gcur[b];
    if (L > BPAD) L = BPAD;
    hist[tid] = 0;
    __syncthreads();

    const int* base = packed + (size_t)b * BPAD;
    for (int i = tid; i < L; i += 256)
        atomicAdd(&hist[base[i] & 255], 1);
    __syncthreads();

    int v = hist[tid];
    off[tid] = v;
    __syncthreads();
    for (int dd = 1; dd < 256; dd <<= 1) {
        int t = (tid >= dd) ? off[tid - dd] : 0;
        __syncthreads();
        off[tid] += t;
        __syncthreads();
    }
    int excl = off[tid] - v;

    int node = b * 256 + tid;
    if (node < n)
        nodeinfo[node] = make_int2(b * BPAD + excl, v);

    hist[tid] = excl;           // reuse as cursor
    __syncthreads();
    for (int i = tid; i < L; i += 256) {
        int pk = base[i];
        int p = atomicAdd(&hist[pk & 255], 1);
        col[(size_t)b * BPAD + p] = pk >> 8;
    }
}

// ---------------------------------------------------------------------------
// dual MFMA GEMM v3: weights staged in LDS (padded rows, 2-way banks), A
// prefetched to regs before the staging barrier -> no global latency in the
// MFMA loop.  T(bf16) = A@W1 ; U(bf16) = A@W2 + bias.  Safe for U == A.
// LDS: 256 rows x HP shorts = 69.6 KB; epilogue hs (17.4 KB) aliases it
// (weights dead after the post-loop barrier).  2 blocks/CU.
// ---------------------------------------------------------------------------
template <int AF32>
__global__ __launch_bounds__(512) void gemm_dual_v3(
        const void* __restrict__ Ain,
        const unsigned short* __restrict__ Wt1,
        const unsigned short* __restrict__ Wt2,
        const float* __restrict__ bias,
        unsigned short* __restrict__ T,
        unsigned short* __restrict__ U, int M) {
    __shared__ __align__(16) unsigned short wlds[WROWS * HP];   // 69632 B
    unsigned short* hs = wlds;                                  // epilogue alias

    int tid = threadIdx.x;
    int wave = tid >> 6;
    int lane = tid & 63;
    int rg = wave >> 1;          // row tile 0..3 (16 rows each)
    int ch = wave & 1;           // col half 0..1 (64 cols each)
    int lrow = lane & 15;
    int koff = (lane >> 4) * 8;
    int row0 = blockIdx.x * 64;

    // ---- stage both weight matrices into LDS (row-padded) ----
    {
        int r16 = tid >> 4;          // 0..31: row within pass
        int c8 = tid & 15;           // 16-byte chunk within row
        #pragma unroll
        for (int p = 0; p < 8; ++p) {
            int row = p * 32 + r16;                  // 0..255
            const unsigned short* src = (row < H ? Wt1 + (size_t)row * H
                                                 : Wt2 + (size_t)(row - H) * H);
            *(uint4*)(wlds + row * HP + c8 * 8) = *(const uint4*)(src + c8 * 8);
        }
    }

    // ---- prefetch A fragments (global; independent of LDS staging) ----
    int arow = row0 + rg * 16 + lrow;
    if (arow >= M) arow = M - 1;          // clamp reads; stores guarded
    bf16x8 af[4];
    #pragma unroll
    for (int kt = 0; kt < 4; ++kt) {
        int k = kt * 32 + koff;
        if (AF32) {
            const float* Arow = (const float*)Ain + (size_t)arow * H;
            float4 a0 = *(const float4*)(Arow + k);
            float4 a1 = *(const float4*)(Arow + k + 4);
            af[kt][0] = (short)f2bf(a0.x); af[kt][1] = (short)f2bf(a0.y);
            af[kt][2] = (short)f2bf(a0.z); af[kt][3] = (short)f2bf(a0.w);
            af[kt][4] = (short)f2bf(a1.x); af[kt][5] = (short)f2bf(a1.y);
            af[kt][6] = (short)f2bf(a1.z); af[kt][7] = (short)f2bf(a1.w);
        } else {
            af[kt] = *(const bf16x8*)((const unsigned short*)Ain + (size_t)arow * H + k);
        }
    }
    __syncthreads();

    // ---- MFMA loop: all operands from regs/LDS ----
    f32x4 accT[4] = {};
    f32x4 accU[4] = {};
    #pragma unroll
    for (int kt = 0; kt < 4; ++kt) {
        int k = kt * 32 + koff;
        #pragma unroll
        for (int nt = 0; nt < 4; ++nt) {
            int c = ch * 64 + nt * 16 + lrow;
            bf16x8 b1 = *(const bf16x8*)(wlds + c * HP + k);
            bf16x8 b2 = *(const bf16x8*)(wlds + H * HP + c * HP + k);
            accT[nt] = __builtin_amdgcn_mfma_f32_16x16x32_bf16(af[kt], b1, accT[nt], 0, 0, 0);
            accU[nt] = __builtin_amdgcn_mfma_f32_16x16x32_bf16(af[kt], b2, accU[nt], 0, 0, 0);
        }
    }
    __syncthreads();     // weights dead; hs region reused below

    int erow = rg * 16 + (lane >> 4) * 4;    // C/D: col=lane&15, row=(lane>>4)*4+i
    // ---- T epilogue ----
    #pragma unroll
    for (int nt = 0; nt < 4; ++nt) {
        int c = ch * 64 + nt * 16 + lrow;
        #pragma unroll
        for (int i = 0; i < 4; ++i)
            hs[(erow + i) * HP + c] = f2bf(accT[nt][i]);
    }
    __syncthreads();
    #pragma unroll
    for (int q = 0; q < 2; ++q) {
        int idx = q * 512 + tid;             // 1024 chunks of 16B: 64 rows x 16 chunks
        int row = idx >> 4, c16 = idx & 15;
        int r = row0 + row;
        if (r < M)
            *(uint4*)(T + (size_t)r * H + c16 * 8) = *(const uint4*)(hs + row * HP + c16 * 8);
    }
    __syncthreads();
    // ---- U epilogue (bias added here) ----
    #pragma unroll
    for (int nt = 0; nt < 4; ++nt) {
        int c = ch * 64 + nt * 16 + lrow;
        float bv = bias[c];
        #pragma unroll
        for (int i = 0; i < 4; ++i)
            hs[(erow + i) * HP + c] = f2bf(accU[nt][i] + bv);
    }
    __syncthreads();
    #pragma unroll
    for (int q = 0; q < 2; ++q) {
        int idx = q * 512 + tid;
        int row = idx >> 4, c16 = idx & 15;
        int r = row0 + row;
        if (r < M)
            *(uint4*)(U + (size_t)r * H + c16 * 8) = *(const uint4*)(hs + row * HP + c16 * 8);
    }
}

// ---------------------------------------------------------------------------
// single MFMA GEMM v3: one weight matrix in LDS; out(f32) = A(bf16)@W + bias
// ---------------------------------------------------------------------------
__global__ __launch_bounds__(512) void gemm_single_v3(
        const unsigned short* __restrict__ A,
        const unsigned short* __restrict__ Wt,
        const float* __restrict__ bias,
        float* __restrict__ out, int M) {
    __shared__ __align__(16) unsigned short wlds[H * HP];   // 34816 B
    int tid = threadIdx.x;
    int wave = tid >> 6;
    int lane = tid & 63;
    int rg = wave >> 1;
    int ch = wave & 1;
    int lrow = lane & 15;
    int koff = (lane >> 4) * 8;
    int row0 = blockIdx.x * 64;

    {
        int r16 = tid >> 4;
        int c8 = tid & 15;
        #pragma unroll
        for (int p = 0; p < 4; ++p) {
            int row = p * 32 + r16;                  // 0..127
            *(uint4*)(wlds + row * HP + c8 * 8) =
                *(const uint4*)(Wt + (size_t)row * H + c8 * 8);
        }
    }

    int arow = row0 + rg * 16 + lrow;
    if (arow >= M) arow = M - 1;
    bf16x8 af[4];
    #pragma unroll
    for (int kt = 0; kt < 4; ++kt)
        af[kt] = *(const bf16x8*)(A + (size_t)arow * H + kt * 32 + koff);
    __syncthreads();

    f32x4 acc[4] = {};
    #pragma unroll
    for (int kt = 0; kt < 4; ++kt) {
        int k = kt * 32 + koff;
        #pragma unroll
        for (int nt = 0; nt < 4; ++nt) {
            int c = ch * 64 + nt * 16 + lrow;
            bf16x8 b = *(const bf16x8*)(wlds + c * HP + k);
            acc[nt] = __builtin_amdgcn_mfma_f32_16x16x32_bf16(af[kt], b, acc[nt], 0, 0, 0);
        }
    }

    int orow = row0 + rg * 16 + (lane >> 4) * 4;
    #pragma unroll
    for (int nt = 0; nt < 4; ++nt) {
        int c = ch * 64 + nt * 16 + lrow;
        float bv = bias[c];
        #pragma unroll
        for (int i = 0; i < 4; ++i) {
            int r = orow + i;
            if (r < M)
                out[(size_t)r * H + c] = acc[nt][i] + bv;
        }
    }
}

// ---------------------------------------------------------------------------
// gather: U[g] = relu( U[g] + sum_{src in adj(g)} T[src] )  (all bf16, in place)
// ---------------------------------------------------------------------------
__global__ __launch_bounds__(256) void gather_relu_b(
        const unsigned short* __restrict__ T,
        const int2* __restrict__ nodeinfo,
        const int* __restrict__ col,
        unsigned short* __restrict__ U, int n) {
    int g = (int)((blockIdx.x * 256u + threadIdx.x) >> 4);
    int lane = threadIdx.x & 15;
    if (g >= n) return;
    int2 info = nodeinfo[g];
    unsigned short* Urow = U + (size_t)g * H + lane * 8;
    uint4 uv = *(const uint4*)Urow;
    float a[8];
    a[0] = bflo(uv.x); a[1] = bfhi(uv.x);
    a[2] = bflo(uv.y); a[3] = bfhi(uv.y);
    a[4] = bflo(uv.z); a[5] = bfhi(uv.z);
    a[6] = bflo(uv.w); a[7] = bfhi(uv.w);
    for (int e0 = 0; e0 < info.y; e0 += 16) {
        int myc = (e0 + lane < info.y) ? col[info.x + e0 + lane] : 0;
        int cnt = min(16, info.y - e0);
        for (int j = 0; j < cnt; ++j) {
            int src = __shfl(myc, j, 16);
            uint4 v = *(const uint4*)(T + (size_t)src * H + lane * 8);
            a[0] += bflo(v.x); a[1] += bfhi(v.x);
            a[2] += bflo(v.y); a[3] += bfhi(v.y);
            a[4] += bflo(v.z); a[5] += bfhi(v.z);
            a[6] += bflo(v.w); a[7] += bfhi(v.w);
        }
    }
    #pragma unroll
    for (int j = 0; j < 8; ++j) a[j] = fmaxf(a[j], 0.f);
    uint4 pk;
    pk.x = packbf(a[0], a[1]);
    pk.y = packbf(a[2], a[3]);
    pk.z = packbf(a[4], a[5]);
    pk.w = packbf(a[6], a[7]);
    *(uint4*)Urow = pk;
}

extern "C" void kernel_launch(void* const* d_in, const int* in_sizes, int n_in,
                              void* d_out, int out_size, void* d_ws, size_t ws_size,
                              hipStream_t stream) {
    const float* x_A  = (const float*)d_in[0];
    const int* edge_r0 = (const int*)d_in[2];
    const int* edge_r1 = (const int*)d_in[3];
    const float* wl0 = (const float*)d_in[4];
    const float* bl0 = (const float*)d_in[5];
    const float* w00 = (const float*)d_in[6];
    const float* b00 = (const float*)d_in[7];
    const float* w10 = (const float*)d_in[8];
    const float* b10 = (const float*)d_in[9];
    const float* wl1 = (const float*)d_in[10];
    const float* bl1 = (const float*)d_in[11];
    const float* w01 = (const float*)d_in[12];
    const float* b01 = (const float*)d_in[13];
    const float* w11 = (const float*)d_in[14];
    const float* b11 = (const float*)d_in[15];
    const float* w_out = (const float*)d_in[16];
    const float* b_out = (const float*)d_in[17];

    const int N  = in_sizes[0] / H;       // 100000
    const int E0 = in_sizes[2] / 2;
    const int E1 = in_sizes[3] / 2;
    const int NB = (N + 255) / 256;       // 391 coarse buckets

    char* ws = (char*)d_ws;
    unsigned short* U  = (unsigned short*)ws;            ws += (size_t)N * H * sizeof(short);
    unsigned short* T2 = (unsigned short*)ws;            ws += (size_t)N * H * sizeof(short);
    int*   col        = (int*)ws;                        ws += (size_t)NB * BPAD * sizeof(int);
    int2*  nodeinfo   = (int2*)ws;                       ws += (size_t)N * sizeof(int2);
    int*   gcur       = (int*)ws;                        ws += 512 * sizeof(int);
    unsigned short* Wt_l1 = (unsigned short*)ws;         ws += H * H * sizeof(short);
    unsigned short* Wt_c1 = (unsigned short*)ws;         ws += H * H * sizeof(short);
    unsigned short* Wt_l0 = (unsigned short*)ws;         ws += H * H * sizeof(short);
    unsigned short* Wt_c0 = (unsigned short*)ws;         ws += H * H * sizeof(short);
    unsigned short* Wt_o  = (unsigned short*)ws;         ws += H * H * sizeof(short);
    float* bc1        = (float*)ws;                      ws += H * sizeof(float);
    float* bc0        = (float*)ws;                      ws += H * sizeof(float);

    // d_out overlays: T1 (bf16, 25.6 MB) at offset 0; packed (7.2 MB) above it.
    // Both dead before gemm_single_v3 writes all of d_out as f32.
    unsigned short* T1 = (unsigned short*)d_out;
    int* packed = (int*)((char*)d_out + (size_t)N * H * sizeof(unsigned short));

    prep_weights_t<<<(H * H + 255) / 256, 256, 0, stream>>>(
        wl1, w01, w11, bl1, b01, b11, wl0, w00, w10, bl0, b00, b10, w_out,
        Wt_l1, Wt_c1, Wt_l0, Wt_c0, Wt_o, bc1, bc0);

    const int gemmBlocks = (N + 63) / 64;
    const int gatherBlocks = (N * 16 + 255) / 256;

    // ---- CSR r1 ----
    hipMemsetAsync(gcur, 0, 512 * sizeof(int), stream);
    bucket_scatter<<<(E1 + EPB - 1) / EPB, 256, 0, stream>>>(edge_r1, E1, gcur, packed);
    bucket_build<<<NB, 256, 0, stream>>>(gcur, packed, col, nodeinfo, N);

    // ---- K1: T1 = bf16(x_A@wl1) ; U = bf16(x_A@wc1 + bc1) ----
    gemm_dual_v3<1><<<gemmBlocks, 512, 0, stream>>>(x_A, Wt_l1, Wt_c1, bc1, T1, U, N);

    // ---- G1: h1 = relu(U + gather_r1(T1)) -> U ----
    gather_relu_b<<<gatherBlocks, 256, 0, stream>>>(T1, nodeinfo, col, U, N);

    // ---- CSR r0 ----
    hipMemsetAsync(gcur, 0, 512 * sizeof(int), stream);
    bucket_scatter<<<(E0 + EPB - 1) / EPB, 256, 0, stream>>>(edge_r0, E0, gcur, packed);
    bucket_build<<<NB, 256, 0, stream>>>(gcur, packed, col, nodeinfo, N);

    // ---- K2: T2 = bf16(h1@wl0) ; U = bf16(h1@wc0 + bc0) (in place) ----
    gemm_dual_v3<0><<<gemmBlocks, 512, 0, stream>>>(U, Wt_l0, Wt_c0, bc0, T2, U, N);

    // ---- G2: h2 = relu(U + gather_r0(T2)) -> U ----
    gather_relu_b<<<gatherBlocks, 256, 0, stream>>>(T2, nodeinfo, col, U, N);

    // ---- K3: out = h2 @ w_out + b_out (f32, overwrites all of d_out) ----
    gemm_single_v3<<<gemmBlocks, 512, 0, stream>>>(U, Wt_o, b_out, (float*)d_out, N);
}

// Round 12
// 254.854 us; speedup vs baseline: 1.7666x; 1.1051x over previous
//
#include <hip/hip_runtime.h>
#include <hip/hip_bf16.h>

#define H 128
#define BPAD 4608            // padded per-bucket capacity (mean 4096, ~8 sigma)
#define EPB 4096             // edges per scatter block
#define HP 136               // padded LDS row stride (shorts): 2-way banks on b128 reads
#define WROWS (2 * H)        // 256 weight rows staged (two matrices)

typedef __attribute__((ext_vector_type(8))) short bf16x8;
typedef __attribute__((ext_vector_type(4))) float f32x4;

static __device__ __forceinline__ unsigned short f2bf(float f) {
    unsigned u = __float_as_uint(f);
    u += 0x7FFFu + ((u >> 16) & 1u);          // round-to-nearest-even
    return (unsigned short)(u >> 16);
}
static __device__ __forceinline__ float bflo(unsigned u) {
    return __uint_as_float(u << 16);
}
static __device__ __forceinline__ float bfhi(unsigned u) {
    return __uint_as_float(u & 0xFFFF0000u);
}
static __device__ __forceinline__ unsigned packbf(float a, float b) {
    return (unsigned)f2bf(a) | ((unsigned)f2bf(b) << 16);
}

// ---------------------------------------------------------------------------
// prep: transposed bf16 weights  Wt[c][k] = bf16(W[k][c])  (+ combined wc, bc)
// ---------------------------------------------------------------------------
__global__ __launch_bounds__(256) void prep_weights_t(
        const float* __restrict__ wl1, const float* __restrict__ w01,
        const float* __restrict__ w11, const float* __restrict__ bl1,
        const float* __restrict__ b01, const float* __restrict__ b11,
        const float* __restrict__ wl0, const float* __restrict__ w00,
        const float* __restrict__ w10, const float* __restrict__ bl0,
        const float* __restrict__ b00, const float* __restrict__ b10,
        const float* __restrict__ w_out,
        unsigned short* __restrict__ Wt_l1, unsigned short* __restrict__ Wt_c1,
        unsigned short* __restrict__ Wt_l0, unsigned short* __restrict__ Wt_c0,
        unsigned short* __restrict__ Wt_o,
        float* __restrict__ bc1, float* __restrict__ bc0) {
    int i = blockIdx.x * 256 + threadIdx.x;     // i = k*H + c
    if (i < H * H) {
        int k = i >> 7, c = i & (H - 1);
        int t = c * H + k;
        Wt_l1[t] = f2bf(wl1[i]);
        Wt_c1[t] = f2bf(w01[i] + w11[i]);
        Wt_l0[t] = f2bf(wl0[i]);
        Wt_c0[t] = f2bf(w00[i] + w10[i]);
        Wt_o[t]  = f2bf(w_out[i]);
        if (i < H) {
            bc1[i] = bl1[i] + b01[i] + b11[i];
            bc0[i] = bl0[i] + b00[i] + b10[i];
        }
    }
}

// ---------------------------------------------------------------------------
// CSR phase 1 (both relations in one launch): coarse-bucket scatter.
// bucket = dst>>8.  Block b < nb1 handles relation 1 edges, else relation 0.
// gcur layout: [rel*512 + bucket].  packed: rel-specific buffer.
// ---------------------------------------------------------------------------
__global__ __launch_bounds__(512) void bucket_scatter2(
        const int* __restrict__ edge1, int E1, int nb1,
        const int* __restrict__ edge0, int E0,
        int* __restrict__ gcur,
        int* __restrict__ packed1, int* __restrict__ packed0) {
    __shared__ int lhist[512];
    __shared__ int lcur[512];
    int tid = threadIdx.x;
    lhist[tid] = 0;
    __syncthreads();

    int rel1 = (blockIdx.x < (unsigned)nb1);
    const int* edge = rel1 ? edge1 : edge0;
    int E = rel1 ? E1 : E0;
    int* packed = rel1 ? packed1 : packed0;
    int* gc = gcur + (rel1 ? 0 : 512);
    int e0 = (rel1 ? blockIdx.x : blockIdx.x - nb1) * EPB;

    int d[8], s[8];
    #pragma unroll
    for (int j = 0; j < 8; ++j) {
        int e = e0 + j * 512 + tid;
        bool v = (e < E);
        d[j] = v ? edge[e] : -1;
        s[j] = v ? edge[E + e] : 0;
        if (v) atomicAdd(&lhist[d[j] >> 8], 1);
    }
    __syncthreads();

    {
        int c = lhist[tid];
        lcur[tid] = (c > 0) ? atomicAdd(&gc[tid], c) : 0;
    }
    __syncthreads();

    #pragma unroll
    for (int j = 0; j < 8; ++j) {
        if (d[j] >= 0) {
            int b = d[j] >> 8;
            int p = atomicAdd(&lcur[b], 1);
            if (p < BPAD)
                packed[(size_t)b * BPAD + p] = (s[j] << 8) | (d[j] & 255);
        }
    }
}

// ---------------------------------------------------------------------------
// CSR phase 2 (both relations in one launch): per-bucket fine build.
// grid = 2*NB blocks; block < NB -> relation 1, else relation 0.
// ---------------------------------------------------------------------------
__global__ __launch_bounds__(512) void bucket_build2(
        const int* __restrict__ gcur,
        const int* __restrict__ packed1, const int* __restrict__ packed0,
        int* __restrict__ col1, int* __restrict__ col0,
        int2* __restrict__ ni1, int2* __restrict__ ni0,
        int nb, int n) {
    __shared__ int hist[256];
    __shared__ int off[256];
    int tid = threadIdx.x;
    int rel1 = (blockIdx.x < (unsigned)nb);
    int b = rel1 ? blockIdx.x : blockIdx.x - nb;
    const int* packed = rel1 ? packed1 : packed0;
    int* col = rel1 ? col1 : col0;
    int2* nodeinfo = rel1 ? ni1 : ni0;

    int L = gcur[(rel1 ? 0 : 512) + b];
    if (L > BPAD) L = BPAD;
    if (tid < 256) hist[tid] = 0;
    __syncthreads();

    const int* base = packed + (size_t)b * BPAD;
    for (int i = tid; i < L; i += 512)
        atomicAdd(&hist[base[i] & 255], 1);
    __syncthreads();

    if (tid < 256) {
        int v = hist[tid];
        off[tid] = v;
    }
    __syncthreads();
    for (int dd = 1; dd < 256; dd <<= 1) {
        int t = 0;
        if (tid < 256 && tid >= dd) t = off[tid - dd];
        __syncthreads();
        if (tid < 256) off[tid] += t;
        __syncthreads();
    }
    if (tid < 256) {
        int v = hist[tid];
        int excl = off[tid] - v;
        int node = b * 256 + tid;
        if (node < n)
            nodeinfo[node] = make_int2(b * BPAD + excl, v);
        hist[tid] = excl;           // reuse as cursor
    }
    __syncthreads();
    for (int i = tid; i < L; i += 512) {
        int pk = base[i];
        int p = atomicAdd(&hist[pk & 255], 1);
        col[(size_t)b * BPAD + p] = pk >> 8;
    }
}

// ---------------------------------------------------------------------------
// dual MFMA GEMM v3: weights staged in LDS (padded rows, 2-way banks), A
// prefetched to regs before the staging barrier -> no global latency in the
// MFMA loop.  T(bf16) = A@W1 ; U(bf16) = A@W2 + bias.  Safe for U == A.
// LDS: 256 rows x HP shorts = 69.6 KB; epilogue hs (17.4 KB) aliases it.
// ---------------------------------------------------------------------------
template <int AF32>
__global__ __launch_bounds__(512) void gemm_dual_v3(
        const void* __restrict__ Ain,
        const unsigned short* __restrict__ Wt1,
        const unsigned short* __restrict__ Wt2,
        const float* __restrict__ bias,
        unsigned short* __restrict__ T,
        unsigned short* __restrict__ U, int M) {
    __shared__ __align__(16) unsigned short wlds[WROWS * HP];   // 69632 B
    unsigned short* hs = wlds;                                  // epilogue alias

    int tid = threadIdx.x;
    int wave = tid >> 6;
    int lane = tid & 63;
    int rg = wave >> 1;          // row tile 0..3 (16 rows each)
    int ch = wave & 1;           // col half 0..1 (64 cols each)
    int lrow = lane & 15;
    int koff = (lane >> 4) * 8;
    int row0 = blockIdx.x * 64;

    // ---- stage both weight matrices into LDS (row-padded) ----
    {
        int r16 = tid >> 4;          // 0..31: row within pass
        int c8 = tid & 15;           // 16-byte chunk within row
        #pragma unroll
        for (int p = 0; p < 8; ++p) {
            int row = p * 32 + r16;                  // 0..255
            const unsigned short* src = (row < H ? Wt1 + (size_t)row * H
                                                 : Wt2 + (size_t)(row - H) * H);
            *(uint4*)(wlds + row * HP + c8 * 8) = *(const uint4*)(src + c8 * 8);
        }
    }

    // ---- prefetch A fragments (global; independent of LDS staging) ----
    int arow = row0 + rg * 16 + lrow;
    if (arow >= M) arow = M - 1;          // clamp reads; stores guarded
    bf16x8 af[4];
    #pragma unroll
    for (int kt = 0; kt < 4; ++kt) {
        int k = kt * 32 + koff;
        if (AF32) {
            const float* Arow = (const float*)Ain + (size_t)arow * H;
            float4 a0 = *(const float4*)(Arow + k);
            float4 a1 = *(const float4*)(Arow + k + 4);
            af[kt][0] = (short)f2bf(a0.x); af[kt][1] = (short)f2bf(a0.y);
            af[kt][2] = (short)f2bf(a0.z); af[kt][3] = (short)f2bf(a0.w);
            af[kt][4] = (short)f2bf(a1.x); af[kt][5] = (short)f2bf(a1.y);
            af[kt][6] = (short)f2bf(a1.z); af[kt][7] = (short)f2bf(a1.w);
        } else {
            af[kt] = *(const bf16x8*)((const unsigned short*)Ain + (size_t)arow * H + k);
        }
    }
    __syncthreads();

    // ---- MFMA loop: all operands from regs/LDS ----
    f32x4 accT[4] = {};
    f32x4 accU[4] = {};
    #pragma unroll
    for (int kt = 0; kt < 4; ++kt) {
        int k = kt * 32 + koff;
        #pragma unroll
        for (int nt = 0; nt < 4; ++nt) {
            int c = ch * 64 + nt * 16 + lrow;
            bf16x8 b1 = *(const bf16x8*)(wlds + c * HP + k);
            bf16x8 b2 = *(const bf16x8*)(wlds + H * HP + c * HP + k);
            accT[nt] = __builtin_amdgcn_mfma_f32_16x16x32_bf16(af[kt], b1, accT[nt], 0, 0, 0);
            accU[nt] = __builtin_amdgcn_mfma_f32_16x16x32_bf16(af[kt], b2, accU[nt], 0, 0, 0);
        }
    }
    __syncthreads();     // weights dead; hs region reused below

    int erow = rg * 16 + (lane >> 4) * 4;    // C/D: col=lane&15, row=(lane>>4)*4+i
    // ---- T epilogue ----
    #pragma unroll
    for (int nt = 0; nt < 4; ++nt) {
        int c = ch * 64 + nt * 16 + lrow;
        #pragma unroll
        for (int i = 0; i < 4; ++i)
            hs[(erow + i) * HP + c] = f2bf(accT[nt][i]);
    }
    __syncthreads();
    #pragma unroll
    for (int q = 0; q < 2; ++q) {
        int idx = q * 512 + tid;             // 1024 chunks of 16B: 64 rows x 16 chunks
        int row = idx >> 4, c16 = idx & 15;
        int r = row0 + row;
        if (r < M)
            *(uint4*)(T + (size_t)r * H + c16 * 8) = *(const uint4*)(hs + row * HP + c16 * 8);
    }
    __syncthreads();
    // ---- U epilogue (bias added here) ----
    #pragma unroll
    for (int nt = 0; nt < 4; ++nt) {
        int c = ch * 64 + nt * 16 + lrow;
        float bv = bias[c];
        #pragma unroll
        for (int i = 0; i < 4; ++i)
            hs[(erow + i) * HP + c] = f2bf(accU[nt][i] + bv);
    }
    __syncthreads();
    #pragma unroll
    for (int q = 0; q < 2; ++q) {
        int idx = q * 512 + tid;
        int row = idx >> 4, c16 = idx & 15;
        int r = row0 + row;
        if (r < M)
            *(uint4*)(U + (size_t)r * H + c16 * 8) = *(const uint4*)(hs + row * HP + c16 * 8);
    }
}

// ---------------------------------------------------------------------------
// single MFMA GEMM v3: one weight matrix in LDS; out(f32) = A(bf16)@W + bias
// ---------------------------------------------------------------------------
__global__ __launch_bounds__(512) void gemm_single_v3(
        const unsigned short* __restrict__ A,
        const unsigned short* __restrict__ Wt,
        const float* __restrict__ bias,
        float* __restrict__ out, int M) {
    __shared__ __align__(16) unsigned short wlds[H * HP];   // 34816 B
    int tid = threadIdx.x;
    int wave = tid >> 6;
    int lane = tid & 63;
    int rg = wave >> 1;
    int ch = wave & 1;
    int lrow = lane & 15;
    int koff = (lane >> 4) * 8;
    int row0 = blockIdx.x * 64;

    {
        int r16 = tid >> 4;
        int c8 = tid & 15;
        #pragma unroll
        for (int p = 0; p < 4; ++p) {
            int row = p * 32 + r16;                  // 0..127
            *(uint4*)(wlds + row * HP + c8 * 8) =
                *(const uint4*)(Wt + (size_t)row * H + c8 * 8);
        }
    }

    int arow = row0 + rg * 16 + lrow;
    if (arow >= M) arow = M - 1;
    bf16x8 af[4];
    #pragma unroll
    for (int kt = 0; kt < 4; ++kt)
        af[kt] = *(const bf16x8*)(A + (size_t)arow * H + kt * 32 + koff);
    __syncthreads();

    f32x4 acc[4] = {};
    #pragma unroll
    for (int kt = 0; kt < 4; ++kt) {
        int k = kt * 32 + koff;
        #pragma unroll
        for (int nt = 0; nt < 4; ++nt) {
            int c = ch * 64 + nt * 16 + lrow;
            bf16x8 b = *(const bf16x8*)(wlds + c * HP + k);
            acc[nt] = __builtin_amdgcn_mfma_f32_16x16x32_bf16(af[kt], b, acc[nt], 0, 0, 0);
        }
    }

    int orow = row0 + rg * 16 + (lane >> 4) * 4;
    #pragma unroll
    for (int nt = 0; nt < 4; ++nt) {
        int c = ch * 64 + nt * 16 + lrow;
        float bv = bias[c];
        #pragma unroll
        for (int i = 0; i < 4; ++i) {
            int r = orow + i;
            if (r < M)
                out[(size_t)r * H + c] = acc[nt][i] + bv;
        }
    }
}

// ---------------------------------------------------------------------------
// gather: U[g] = relu( U[g] + sum_{src in adj(g)} T[src] )  (all bf16, in place)
// At the L3 random-read floor (FETCH ~= 8 XCD x |T|); leave structure alone.
// ---------------------------------------------------------------------------
__global__ __launch_bounds__(256) void gather_relu_b(
        const unsigned short* __restrict__ T,
        const int2* __restrict__ nodeinfo,
        const int* __restrict__ col,
        unsigned short* __restrict__ U, int n) {
    int g = (int)((blockIdx.x * 256u + threadIdx.x) >> 4);
    int lane = threadIdx.x & 15;
    if (g >= n) return;
    int2 info = nodeinfo[g];
    unsigned short* Urow = U + (size_t)g * H + lane * 8;
    uint4 uv = *(const uint4*)Urow;
    float a[8];
    a[0] = bflo(uv.x); a[1] = bfhi(uv.x);
    a[2] = bflo(uv.y); a[3] = bfhi(uv.y);
    a[4] = bflo(uv.z); a[5] = bfhi(uv.z);
    a[6] = bflo(uv.w); a[7] = bfhi(uv.w);
    for (int e0 = 0; e0 < info.y; e0 += 16) {
        int myc = (e0 + lane < info.y) ? col[info.x + e0 + lane] : 0;
        int cnt = min(16, info.y - e0);
        for (int j = 0; j < cnt; ++j) {
            int src = __shfl(myc, j, 16);
            uint4 v = *(const uint4*)(T + (size_t)src * H + lane * 8);
            a[0] += bflo(v.x); a[1] += bfhi(v.x);
            a[2] += bflo(v.y); a[3] += bfhi(v.y);
            a[4] += bflo(v.z); a[5] += bfhi(v.z);
            a[6] += bflo(v.w); a[7] += bfhi(v.w);
        }
    }
    #pragma unroll
    for (int j = 0; j < 8; ++j) a[j] = fmaxf(a[j], 0.f);
    uint4 pk;
    pk.x = packbf(a[0], a[1]);
    pk.y = packbf(a[2], a[3]);
    pk.z = packbf(a[4], a[5]);
    pk.w = packbf(a[6], a[7]);
    *(uint4*)Urow = pk;
}

extern "C" void kernel_launch(void* const* d_in, const int* in_sizes, int n_in,
                              void* d_out, int out_size, void* d_ws, size_t ws_size,
                              hipStream_t stream) {
    const float* x_A  = (const float*)d_in[0];
    const int* edge_r0 = (const int*)d_in[2];
    const int* edge_r1 = (const int*)d_in[3];
    const float* wl0 = (const float*)d_in[4];
    const float* bl0 = (const float*)d_in[5];
    const float* w00 = (const float*)d_in[6];
    const float* b00 = (const float*)d_in[7];
    const float* w10 = (const float*)d_in[8];
    const float* b10 = (const float*)d_in[9];
    const float* wl1 = (const float*)d_in[10];
    const float* bl1 = (const float*)d_in[11];
    const float* w01 = (const float*)d_in[12];
    const float* b01 = (const float*)d_in[13];
    const float* w11 = (const float*)d_in[14];
    const float* b11 = (const float*)d_in[15];
    const float* w_out = (const float*)d_in[16];
    const float* b_out = (const float*)d_in[17];

    const int N  = in_sizes[0] / H;       // 100000
    const int E0 = in_sizes[2] / 2;
    const int E1 = in_sizes[3] / 2;
    const int NB = (N + 255) / 256;       // 391 coarse buckets

    char* ws = (char*)d_ws;
    unsigned short* U  = (unsigned short*)ws;            ws += (size_t)N * H * sizeof(short);
    unsigned short* T2 = (unsigned short*)ws;            ws += (size_t)N * H * sizeof(short);
    int*   col1       = (int*)ws;                        ws += (size_t)NB * BPAD * sizeof(int);
    int*   col0       = (int*)ws;                        ws += (size_t)NB * BPAD * sizeof(int);
    int2*  ni1        = (int2*)ws;                       ws += (size_t)N * sizeof(int2);
    int2*  ni0        = (int2*)ws;                       ws += (size_t)N * sizeof(int2);
    int*   gcur       = (int*)ws;                        ws += 1024 * sizeof(int);
    unsigned short* Wt_l1 = (unsigned short*)ws;         ws += H * H * sizeof(short);
    unsigned short* Wt_c1 = (unsigned short*)ws;         ws += H * H * sizeof(short);
    unsigned short* Wt_l0 = (unsigned short*)ws;         ws += H * H * sizeof(short);
    unsigned short* Wt_c0 = (unsigned short*)ws;         ws += H * H * sizeof(short);
    unsigned short* Wt_o  = (unsigned short*)ws;         ws += H * H * sizeof(short);
    float* bc1        = (float*)ws;                      ws += H * sizeof(float);
    float* bc0        = (float*)ws;                      ws += H * sizeof(float);

    // d_out overlays: T1 (bf16, 25.6 MB) at 0; packed1/packed0 (7.2 MB each)
    // above it.  All dead before gemm_single_v3 writes d_out as f32.
    unsigned short* T1 = (unsigned short*)d_out;
    int* packed1 = (int*)((char*)d_out + (size_t)N * H * sizeof(unsigned short));
    int* packed0 = packed1 + (size_t)NB * BPAD;

    prep_weights_t<<<(H * H + 255) / 256, 256, 0, stream>>>(
        wl1, w01, w11, bl1, b01, b11, wl0, w00, w10, bl0, b00, b10, w_out,
        Wt_l1, Wt_c1, Wt_l0, Wt_c0, Wt_o, bc1, bc0);

    const int gemmBlocks = (N + 63) / 64;
    const int gatherBlocks = (N * 16 + 255) / 256;
    const int nb1 = (E1 + EPB - 1) / EPB;
    const int nb0 = (E0 + EPB - 1) / EPB;

    // ---- both CSRs up front, one launch per phase ----
    hipMemsetAsync(gcur, 0, 1024 * sizeof(int), stream);
    bucket_scatter2<<<nb1 + nb0, 512, 0, stream>>>(edge_r1, E1, nb1, edge_r0, E0,
                                                   gcur, packed1, packed0);
    bucket_build2<<<2 * NB, 512, 0, stream>>>(gcur, packed1, packed0,
                                              col1, col0, ni1, ni0, NB, N);

    // ---- K1: T1 = bf16(x_A@wl1) ; U = bf16(x_A@wc1 + bc1) ----
    gemm_dual_v3<1><<<gemmBlocks, 512, 0, stream>>>(x_A, Wt_l1, Wt_c1, bc1, T1, U, N);

    // ---- G1: h1 = relu(U + gather_r1(T1)) -> U ----
    gather_relu_b<<<gatherBlocks, 256, 0, stream>>>(T1, ni1, col1, U, N);

    // ---- K2: T2 = bf16(h1@wl0) ; U = bf16(h1@wc0 + bc0) (in place) ----
    gemm_dual_v3<0><<<gemmBlocks, 512, 0, stream>>>(U, Wt_l0, Wt_c0, bc0, T2, U, N);

    // ---- G2: h2 = relu(U + gather_r0(T2)) -> U ----
    gather_relu_b<<<gatherBlocks, 256, 0, stream>>>(T2, ni0, col0, U, N);

    // ---- K3: out = h2 @ w_out + b_out (f32, overwrites all of d_out) ----
    gemm_single_v3<<<gemmBlocks, 512, 0, stream>>>(U, Wt_o, b_out, (float*)d_out, N);
}

// Round 13
// 244.016 us; speedup vs baseline: 1.8451x; 1.0444x over previous
//
#include <hip/hip_runtime.h>
#include <hip/hip_bf16.h>

#define H 128
#define BPAD 4608            // padded per-bucket capacity (mean 4096, ~8 sigma)
#define EPB 4096             // edges per scatter block
#define HP 136               // padded LDS row stride (shorts): 2-way banks on b128 reads
#define WROWS (2 * H)        // 256 weight rows staged (two matrices)

typedef __attribute__((ext_vector_type(8))) short bf16x8;
typedef __attribute__((ext_vector_type(4))) float f32x4;

static __device__ __forceinline__ unsigned short f2bf(float f) {
    unsigned u = __float_as_uint(f);
    u += 0x7FFFu + ((u >> 16) & 1u);          // round-to-nearest-even
    return (unsigned short)(u >> 16);
}
static __device__ __forceinline__ float bflo(unsigned u) {
    return __uint_as_float(u << 16);
}
static __device__ __forceinline__ float bfhi(unsigned u) {
    return __uint_as_float(u & 0xFFFF0000u);
}
static __device__ __forceinline__ unsigned packbf(float a, float b) {
    return (unsigned)f2bf(a) | ((unsigned)f2bf(b) << 16);
}

// ---------------------------------------------------------------------------
// prep: transposed bf16 weights + combined wc/bc + zero gcur (memset fused)
// ---------------------------------------------------------------------------
__global__ __launch_bounds__(256) void prep_weights_t(
        const float* __restrict__ wl1, const float* __restrict__ w01,
        const float* __restrict__ w11, const float* __restrict__ bl1,
        const float* __restrict__ b01, const float* __restrict__ b11,
        const float* __restrict__ wl0, const float* __restrict__ w00,
        const float* __restrict__ w10, const float* __restrict__ bl0,
        const float* __restrict__ b00, const float* __restrict__ b10,
        const float* __restrict__ w_out,
        unsigned short* __restrict__ Wt_l1, unsigned short* __restrict__ Wt_c1,
        unsigned short* __restrict__ Wt_l0, unsigned short* __restrict__ Wt_c0,
        unsigned short* __restrict__ Wt_o,
        float* __restrict__ bc1, float* __restrict__ bc0,
        int* __restrict__ gcur) {
    int i = blockIdx.x * 256 + threadIdx.x;     // i = k*H + c
    if (i < H * H) {
        int k = i >> 7, c = i & (H - 1);
        int t = c * H + k;
        Wt_l1[t] = f2bf(wl1[i]);
        Wt_c1[t] = f2bf(w01[i] + w11[i]);
        Wt_l0[t] = f2bf(wl0[i]);
        Wt_c0[t] = f2bf(w00[i] + w10[i]);
        Wt_o[t]  = f2bf(w_out[i]);
        if (i < H) {
            bc1[i] = bl1[i] + b01[i] + b11[i];
            bc0[i] = bl0[i] + b00[i] + b10[i];
        }
        if (i < 1024) gcur[i] = 0;
    }
}

// ---------------------------------------------------------------------------
// scatter body (512 threads): coarse-bucket scatter for one relation chunk
// ---------------------------------------------------------------------------
static __device__ __forceinline__ void scatter_body(
        const int* __restrict__ edge, int E, int e0,
        int* __restrict__ gc, int* __restrict__ packed,
        int* __restrict__ lhist, int* __restrict__ lcur) {
    int tid = threadIdx.x;
    lhist[tid] = 0;
    __syncthreads();

    int d[8], s[8];
    #pragma unroll
    for (int j = 0; j < 8; ++j) {
        int e = e0 + j * 512 + tid;
        bool v = (e < E);
        d[j] = v ? edge[e] : -1;
        s[j] = v ? edge[E + e] : 0;
        if (v) atomicAdd(&lhist[d[j] >> 8], 1);
    }
    __syncthreads();

    {
        int c = lhist[tid];
        lcur[tid] = (c > 0) ? atomicAdd(&gc[tid], c) : 0;
    }
    __syncthreads();

    #pragma unroll
    for (int j = 0; j < 8; ++j) {
        if (d[j] >= 0) {
            int b = d[j] >> 8;
            int p = atomicAdd(&lcur[b], 1);
            if (p < BPAD)
                packed[(size_t)b * BPAD + p] = (s[j] << 8) | (d[j] & 255);
        }
    }
}

// ---------------------------------------------------------------------------
// build body (512 threads): per-bucket fine build -> nodeinfo + col
// ---------------------------------------------------------------------------
static __device__ __forceinline__ void build_body(
        const int* __restrict__ packed, int L, int b,
        int* __restrict__ col, int2* __restrict__ nodeinfo, int n,
        int* __restrict__ hist, int* __restrict__ off) {
    int tid = threadIdx.x;
    if (L > BPAD) L = BPAD;
    if (tid < 256) hist[tid] = 0;
    __syncthreads();

    const int* base = packed + (size_t)b * BPAD;
    for (int i = tid; i < L; i += 512)
        atomicAdd(&hist[base[i] & 255], 1);
    __syncthreads();

    if (tid < 256) off[tid] = hist[tid];
    __syncthreads();
    for (int dd = 1; dd < 256; dd <<= 1) {
        int t = 0;
        if (tid < 256 && tid >= dd) t = off[tid - dd];
        __syncthreads();
        if (tid < 256) off[tid] += t;
        __syncthreads();
    }
    if (tid < 256) {
        int v = hist[tid];
        int excl = off[tid] - v;
        int node = b * 256 + tid;
        if (node < n)
            nodeinfo[node] = make_int2(b * BPAD + excl, v);
        hist[tid] = excl;           // reuse as cursor
    }
    __syncthreads();
    for (int i = tid; i < L; i += 512) {
        int pk = base[i];
        int p = atomicAdd(&hist[pk & 255], 1);
        col[(size_t)b * BPAD + p] = pk >> 8;
    }
}

// ---------------------------------------------------------------------------
// dual GEMM body (512 threads): weights from LDS (padded), A prefetched.
// T(bf16) = A@W1 ; U(bf16) = A@W2 + bias.  Safe for U == A.
// ---------------------------------------------------------------------------
template <int AF32>
static __device__ __forceinline__ void gemm_dual_body(
        const void* __restrict__ Ain,
        const unsigned short* __restrict__ Wt1,
        const unsigned short* __restrict__ Wt2,
        const float* __restrict__ bias,
        unsigned short* __restrict__ T,
        unsigned short* __restrict__ U, int M,
        unsigned short* __restrict__ wlds, int blk) {
    unsigned short* hs = wlds;                  // epilogue alias

    int tid = threadIdx.x;
    int wave = tid >> 6;
    int lane = tid & 63;
    int rg = wave >> 1;          // row tile 0..3 (16 rows each)
    int ch = wave & 1;           // col half 0..1 (64 cols each)
    int lrow = lane & 15;
    int koff = (lane >> 4) * 8;
    int row0 = blk * 64;

    // ---- stage both weight matrices into LDS (row-padded) ----
    {
        int r16 = tid >> 4;          // 0..31
        int c8 = tid & 15;
        #pragma unroll
        for (int p = 0; p < 8; ++p) {
            int row = p * 32 + r16;                  // 0..255
            const unsigned short* src = (row < H ? Wt1 + (size_t)row * H
                                                 : Wt2 + (size_t)(row - H) * H);
            *(uint4*)(wlds + row * HP + c8 * 8) = *(const uint4*)(src + c8 * 8);
        }
    }

    // ---- prefetch A fragments ----
    int arow = row0 + rg * 16 + lrow;
    if (arow >= M) arow = M - 1;
    bf16x8 af[4];
    #pragma unroll
    for (int kt = 0; kt < 4; ++kt) {
        int k = kt * 32 + koff;
        if (AF32) {
            const float* Arow = (const float*)Ain + (size_t)arow * H;
            float4 a0 = *(const float4*)(Arow + k);
            float4 a1 = *(const float4*)(Arow + k + 4);
            af[kt][0] = (short)f2bf(a0.x); af[kt][1] = (short)f2bf(a0.y);
            af[kt][2] = (short)f2bf(a0.z); af[kt][3] = (short)f2bf(a0.w);
            af[kt][4] = (short)f2bf(a1.x); af[kt][5] = (short)f2bf(a1.y);
            af[kt][6] = (short)f2bf(a1.z); af[kt][7] = (short)f2bf(a1.w);
        } else {
            af[kt] = *(const bf16x8*)((const unsigned short*)Ain + (size_t)arow * H + k);
        }
    }
    __syncthreads();

    f32x4 accT[4] = {};
    f32x4 accU[4] = {};
    #pragma unroll
    for (int kt = 0; kt < 4; ++kt) {
        int k = kt * 32 + koff;
        #pragma unroll
        for (int nt = 0; nt < 4; ++nt) {
            int c = ch * 64 + nt * 16 + lrow;
            bf16x8 b1 = *(const bf16x8*)(wlds + c * HP + k);
            bf16x8 b2 = *(const bf16x8*)(wlds + H * HP + c * HP + k);
            accT[nt] = __builtin_amdgcn_mfma_f32_16x16x32_bf16(af[kt], b1, accT[nt], 0, 0, 0);
            accU[nt] = __builtin_amdgcn_mfma_f32_16x16x32_bf16(af[kt], b2, accU[nt], 0, 0, 0);
        }
    }
    __syncthreads();     // weights dead; hs reused

    int erow = rg * 16 + (lane >> 4) * 4;
    // ---- T epilogue ----
    #pragma unroll
    for (int nt = 0; nt < 4; ++nt) {
        int c = ch * 64 + nt * 16 + lrow;
        #pragma unroll
        for (int i = 0; i < 4; ++i)
            hs[(erow + i) * HP + c] = f2bf(accT[nt][i]);
    }
    __syncthreads();
    #pragma unroll
    for (int q = 0; q < 2; ++q) {
        int idx = q * 512 + tid;             // 64 rows x 16 uint4 chunks
        int row = idx >> 4, c16 = idx & 15;
        int r = row0 + row;
        if (r < M)
            *(uint4*)(T + (size_t)r * H + c16 * 8) = *(const uint4*)(hs + row * HP + c16 * 8);
    }
    __syncthreads();
    // ---- U epilogue ----
    #pragma unroll
    for (int nt = 0; nt < 4; ++nt) {
        int c = ch * 64 + nt * 16 + lrow;
        float bv = bias[c];
        #pragma unroll
        for (int i = 0; i < 4; ++i)
            hs[(erow + i) * HP + c] = f2bf(accU[nt][i] + bv);
    }
    __syncthreads();
    #pragma unroll
    for (int q = 0; q < 2; ++q) {
        int idx = q * 512 + tid;
        int row = idx >> 4, c16 = idx & 15;
        int r = row0 + row;
        if (r < M)
            *(uint4*)(U + (size_t)r * H + c16 * 8) = *(const uint4*)(hs + row * HP + c16 * 8);
    }
}

// ---------------------------------------------------------------------------
// merged K1 + scatter(both relations): disjoint block ranges, no cross-deps
// ---------------------------------------------------------------------------
__global__ __launch_bounds__(512) void k1_scatter(
        const float* __restrict__ xA,
        const unsigned short* __restrict__ Wt1,
        const unsigned short* __restrict__ Wt2,
        const float* __restrict__ bias,
        unsigned short* __restrict__ T,
        unsigned short* __restrict__ U, int M, int gemmBlocks,
        const int* __restrict__ edge1, int E1, int nb1,
        const int* __restrict__ edge0, int E0,
        int* __restrict__ gcur,
        int* __restrict__ packed1, int* __restrict__ packed0) {
    __shared__ __align__(16) unsigned short wlds[WROWS * HP];   // 69632 B
    if ((int)blockIdx.x < gemmBlocks) {
        gemm_dual_body<1>(xA, Wt1, Wt2, bias, T, U, M, wlds, blockIdx.x);
    } else {
        int sb = blockIdx.x - gemmBlocks;
        int rel1 = (sb < nb1);
        int* lhist = (int*)wlds;
        int* lcur = lhist + 512;
        scatter_body(rel1 ? edge1 : edge0, rel1 ? E1 : E0,
                     (rel1 ? sb : sb - nb1) * EPB,
                     gcur + (rel1 ? 0 : 512),
                     rel1 ? packed1 : packed0, lhist, lcur);
    }
}

// ---------------------------------------------------------------------------
// standalone build for relation 1 (must precede G1)
// ---------------------------------------------------------------------------
__global__ __launch_bounds__(512) void build_r1(
        const int* __restrict__ gcur, const int* __restrict__ packed1,
        int* __restrict__ col1, int2* __restrict__ ni1, int n) {
    __shared__ int hist[256];
    __shared__ int off[256];
    build_body(packed1, gcur[blockIdx.x], blockIdx.x, col1, ni1, n, hist, off);
}

// ---------------------------------------------------------------------------
// merged K2 + build(relation 0): build_r0 only needed before G2
// ---------------------------------------------------------------------------
__global__ __launch_bounds__(512) void k2_build(
        const unsigned short* __restrict__ A,
        const unsigned short* __restrict__ Wt1,
        const unsigned short* __restrict__ Wt2,
        const float* __restrict__ bias,
        unsigned short* __restrict__ T,
        unsigned short* __restrict__ U, int M, int gemmBlocks,
        const int* __restrict__ gcur, const int* __restrict__ packed0,
        int* __restrict__ col0, int2* __restrict__ ni0) {
    __shared__ __align__(16) unsigned short wlds[WROWS * HP];   // 69632 B
    if ((int)blockIdx.x < gemmBlocks) {
        gemm_dual_body<0>(A, Wt1, Wt2, bias, T, U, M, wlds, blockIdx.x);
    } else {
        int b = blockIdx.x - gemmBlocks;
        int* hist = (int*)wlds;
        int* off = hist + 256;
        build_body(packed0, gcur[512 + b], b, col0, ni0, M, hist, off);
    }
}

// ---------------------------------------------------------------------------
// single MFMA GEMM v3: out(f32) = A(bf16)@W + bias
// ---------------------------------------------------------------------------
__global__ __launch_bounds__(512) void gemm_single_v3(
        const unsigned short* __restrict__ A,
        const unsigned short* __restrict__ Wt,
        const float* __restrict__ bias,
        float* __restrict__ out, int M) {
    __shared__ __align__(16) unsigned short wlds[H * HP];   // 34816 B
    int tid = threadIdx.x;
    int wave = tid >> 6;
    int lane = tid & 63;
    int rg = wave >> 1;
    int ch = wave & 1;
    int lrow = lane & 15;
    int koff = (lane >> 4) * 8;
    int row0 = blockIdx.x * 64;

    {
        int r16 = tid >> 4;
        int c8 = tid & 15;
        #pragma unroll
        for (int p = 0; p < 4; ++p) {
            int row = p * 32 + r16;                  // 0..127
            *(uint4*)(wlds + row * HP + c8 * 8) =
                *(const uint4*)(Wt + (size_t)row * H + c8 * 8);
        }
    }

    int arow = row0 + rg * 16 + lrow;
    if (arow >= M) arow = M - 1;
    bf16x8 af[4];
    #pragma unroll
    for (int kt = 0; kt < 4; ++kt)
        af[kt] = *(const bf16x8*)(A + (size_t)arow * H + kt * 32 + koff);
    __syncthreads();

    f32x4 acc[4] = {};
    #pragma unroll
    for (int kt = 0; kt < 4; ++kt) {
        int k = kt * 32 + koff;
        #pragma unroll
        for (int nt = 0; nt < 4; ++nt) {
            int c = ch * 64 + nt * 16 + lrow;
            bf16x8 b = *(const bf16x8*)(wlds + c * HP + k);
            acc[nt] = __builtin_amdgcn_mfma_f32_16x16x32_bf16(af[kt], b, acc[nt], 0, 0, 0);
        }
    }

    int orow = row0 + rg * 16 + (lane >> 4) * 4;
    #pragma unroll
    for (int nt = 0; nt < 4; ++nt) {
        int c = ch * 64 + nt * 16 + lrow;
        float bv = bias[c];
        #pragma unroll
        for (int i = 0; i < 4; ++i) {
            int r = orow + i;
            if (r < M)
                out[(size_t)r * H + c] = acc[nt][i] + bv;
        }
    }
}

// ---------------------------------------------------------------------------
// gather: U[g] = relu( U[g] + sum_{src in adj(g)} T[src] )  (all bf16, in place)
// At the compulsory L2-fill floor (~7.1 x |T| FETCH); leave structure alone.
// ---------------------------------------------------------------------------
__global__ __launch_bounds__(256) void gather_relu_b(
        const unsigned short* __restrict__ T,
        const int2* __restrict__ nodeinfo,
        const int* __restrict__ col,
        unsigned short* __restrict__ U, int n) {
    int g = (int)((blockIdx.x * 256u + threadIdx.x) >> 4);
    int lane = threadIdx.x & 15;
    if (g >= n) return;
    int2 info = nodeinfo[g];
    unsigned short* Urow = U + (size_t)g * H + lane * 8;
    uint4 uv = *(const uint4*)Urow;
    float a[8];
    a[0] = bflo(uv.x); a[1] = bfhi(uv.x);
    a[2] = bflo(uv.y); a[3] = bfhi(uv.y);
    a[4] = bflo(uv.z); a[5] = bfhi(uv.z);
    a[6] = bflo(uv.w); a[7] = bfhi(uv.w);
    for (int e0 = 0; e0 < info.y; e0 += 16) {
        int myc = (e0 + lane < info.y) ? col[info.x + e0 + lane] : 0;
        int cnt = min(16, info.y - e0);
        for (int j = 0; j < cnt; ++j) {
            int src = __shfl(myc, j, 16);
            uint4 v = *(const uint4*)(T + (size_t)src * H + lane * 8);
            a[0] += bflo(v.x); a[1] += bfhi(v.x);
            a[2] += bflo(v.y); a[3] += bfhi(v.y);
            a[4] += bflo(v.z); a[5] += bfhi(v.z);
            a[6] += bflo(v.w); a[7] += bfhi(v.w);
        }
    }
    #pragma unroll
    for (int j = 0; j < 8; ++j) a[j] = fmaxf(a[j], 0.f);
    uint4 pk;
    pk.x = packbf(a[0], a[1]);
    pk.y = packbf(a[2], a[3]);
    pk.z = packbf(a[4], a[5]);
    pk.w = packbf(a[6], a[7]);
    *(uint4*)Urow = pk;
}

extern "C" void kernel_launch(void* const* d_in, const int* in_sizes, int n_in,
                              void* d_out, int out_size, void* d_ws, size_t ws_size,
                              hipStream_t stream) {
    const float* x_A  = (const float*)d_in[0];
    const int* edge_r0 = (const int*)d_in[2];
    const int* edge_r1 = (const int*)d_in[3];
    const float* wl0 = (const float*)d_in[4];
    const float* bl0 = (const float*)d_in[5];
    const float* w00 = (const float*)d_in[6];
    const float* b00 = (const float*)d_in[7];
    const float* w10 = (const float*)d_in[8];
    const float* b10 = (const float*)d_in[9];
    const float* wl1 = (const float*)d_in[10];
    const float* bl1 = (const float*)d_in[11];
    const float* w01 = (const float*)d_in[12];
    const float* b01 = (const float*)d_in[13];
    const float* w11 = (const float*)d_in[14];
    const float* b11 = (const float*)d_in[15];
    const float* w_out = (const float*)d_in[16];
    const float* b_out = (const float*)d_in[17];

    const int N  = in_sizes[0] / H;       // 100000
    const int E0 = in_sizes[2] / 2;
    const int E1 = in_sizes[3] / 2;
    const int NB = (N + 255) / 256;       // 391 coarse buckets

    char* ws = (char*)d_ws;
    unsigned short* U  = (unsigned short*)ws;            ws += (size_t)N * H * sizeof(short);
    unsigned short* T2 = (unsigned short*)ws;            ws += (size_t)N * H * sizeof(short);
    int*   col1       = (int*)ws;                        ws += (size_t)NB * BPAD * sizeof(int);
    int*   col0       = (int*)ws;                        ws += (size_t)NB * BPAD * sizeof(int);
    int2*  ni1        = (int2*)ws;                       ws += (size_t)N * sizeof(int2);
    int2*  ni0        = (int2*)ws;                       ws += (size_t)N * sizeof(int2);
    int*   gcur       = (int*)ws;                        ws += 1024 * sizeof(int);
    unsigned short* Wt_l1 = (unsigned short*)ws;         ws += H * H * sizeof(short);
    unsigned short* Wt_c1 = (unsigned short*)ws;         ws += H * H * sizeof(short);
    unsigned short* Wt_l0 = (unsigned short*)ws;         ws += H * H * sizeof(short);
    unsigned short* Wt_c0 = (unsigned short*)ws;         ws += H * H * sizeof(short);
    unsigned short* Wt_o  = (unsigned short*)ws;         ws += H * H * sizeof(short);
    float* bc1        = (float*)ws;                      ws += H * sizeof(float);
    float* bc0        = (float*)ws;                      ws += H * sizeof(float);

    // d_out overlays: T1 (bf16, 25.6 MB) at 0; packed1/packed0 (7.2 MB each)
    // above it.  All dead before gemm_single_v3 writes d_out as f32.
    unsigned short* T1 = (unsigned short*)d_out;
    int* packed1 = (int*)((char*)d_out + (size_t)N * H * sizeof(unsigned short));
    int* packed0 = packed1 + (size_t)NB * BPAD;

    const int gemmBlocks = (N + 63) / 64;
    const int gatherBlocks = (N * 16 + 255) / 256;
    const int nb1 = (E1 + EPB - 1) / EPB;
    const int nb0 = (E0 + EPB - 1) / EPB;

    // ---- prep (weights + biases + gcur zero) ----
    prep_weights_t<<<(H * H + 255) / 256, 256, 0, stream>>>(
        wl1, w01, w11, bl1, b01, b11, wl0, w00, w10, bl0, b00, b10, w_out,
        Wt_l1, Wt_c1, Wt_l0, Wt_c0, Wt_o, bc1, bc0, gcur);

    // ---- K1 + scatter(both relations) ----
    k1_scatter<<<gemmBlocks + nb1 + nb0, 512, 0, stream>>>(
        x_A, Wt_l1, Wt_c1, bc1, T1, U, N, gemmBlocks,
        edge_r1, E1, nb1, edge_r0, E0, gcur, packed1, packed0);

    // ---- build r1 (must precede G1) ----
    build_r1<<<NB, 512, 0, stream>>>(gcur, packed1, col1, ni1, N);

    // ---- G1: h1 = relu(U + gather_r1(T1)) -> U ----
    gather_relu_b<<<gatherBlocks, 256, 0, stream>>>(T1, ni1, col1, U, N);

    // ---- K2 + build r0 ----
    k2_build<<<gemmBlocks + NB, 512, 0, stream>>>(
        U, Wt_l0, Wt_c0, bc0, T2, U, N, gemmBlocks, gcur, packed0, col0, ni0);

    // ---- G2: h2 = relu(U + gather_r0(T2)) -> U ----
    gather_relu_b<<<gatherBlocks, 256, 0, stream>>>(T2, ni0, col0, U, N);

    // ---- K3: out = h2 @ w_out + b_out (f32, overwrites all of d_out) ----
    gemm_single_v3<<<gemmBlocks, 512, 0, stream>>>(U, Wt_o, b_out, (float*)d_out, N);
}